// Round 1
// baseline (605.980 us; speedup 1.0000x reference)
//
#include <hip/hip_runtime.h>
#include <math.h>

// Problem constants
#define T_SEQ 4096
#define DIM   1024
#define NH    8
#define HDIM  64
#define ETA   4
#define NR    7
#define NKQV  2560   // H*HD*5
#define NP    96     // H*ETA*3
#define CHUNK 64
#define NCHUNK 64    // T_SEQ / CHUNK

// Workspace layout (float offsets)
#define KQV_OFF   0ul            // 4096*2560 = 10485760
#define P_OFF     10485760ul     // 4096*96   = 393216
#define OCC_OFF   10878976ul     // 4096*8    = 32768
#define ATTN_OFF  10911744ul     // 4096*512  = 2097152
#define YSUM_OFF  13008896ul     // 64*8*44*64 = 1441792
#define CARRY_OFF 14450688ul     // 64*8*39*64 = 1277952
// total = 15728640 floats = 62.9 MB

// Output layout (float offsets), concatenated in return order
#define O_ATTN 0ul
#define O_FK   4194304ul   // (7,8,256)
#define O_FV   4208640ul   // (7,8,64)
#define O_FS   4212224ul   // (8,256)
#define O_TICK 4214272ul   // (1,)

__device__ __forceinline__ float sigm(float x) { return 1.f / (1.f + __expf(-x)); }

// ---------------------------------------------------------------------------
// Generic f32 GEMM with bias: C[M,N] = A[M,K] @ B[K,N] + bias[N]
// M % 64 == 0, K % 16 == 0, N % 4 == 0 (N guarded).
// block 256 threads, 64x64 tile, BK=16, 4x4 micro-tile per thread.
// ---------------------------------------------------------------------------
__global__ __launch_bounds__(256) void gemm_bias_f32(
    const float* __restrict__ A, const float* __restrict__ B,
    const float* __restrict__ bias, float* __restrict__ C,
    int M, int N, int K) {
  __shared__ __align__(16) float As[16][64];   // transposed A tile [k][m]
  __shared__ __align__(16) float Bs[16][64];   // B tile [k][n]
  const int tid  = threadIdx.x;
  const int tx   = tid & 15;        // n-dim thread coord
  const int ty   = tid >> 4;        // m-dim thread coord
  const int arow = tid >> 2;        // A load: row within tile (0..63)
  const int acg  = (tid & 3) << 2;  // A load: k group (0,4,8,12)
  const int brow = tid >> 4;        // B load: k row (0..15)
  const int bcol = (tid & 15) << 2; // B load: col group
  const int gcolB = blockIdx.x * 64 + bcol;

  const float* Ap = A + (size_t)(blockIdx.y * 64 + arow) * K + acg;
  const float* Bp = B + (size_t)brow * N + gcolB;

  float acc[4][4];
#pragma unroll
  for (int i = 0; i < 4; ++i)
#pragma unroll
    for (int j = 0; j < 4; ++j) acc[i][j] = 0.f;

  for (int k0 = 0; k0 < K; k0 += 16) {
    float4 av = *(const float4*)(Ap + k0);
    float4 bv = make_float4(0.f, 0.f, 0.f, 0.f);
    if (gcolB < N) bv = *(const float4*)(Bp + (size_t)k0 * N);
    __syncthreads();
    As[acg + 0][arow] = av.x;
    As[acg + 1][arow] = av.y;
    As[acg + 2][arow] = av.z;
    As[acg + 3][arow] = av.w;
    *(float4*)(&Bs[brow][bcol]) = bv;
    __syncthreads();
#pragma unroll
    for (int kk = 0; kk < 16; ++kk) {
      float4 a4 = *(const float4*)(&As[kk][ty << 2]);
      float4 b4 = *(const float4*)(&Bs[kk][tx << 2]);
      float ar[4] = {a4.x, a4.y, a4.z, a4.w};
      float br[4] = {b4.x, b4.y, b4.z, b4.w};
#pragma unroll
      for (int i = 0; i < 4; ++i)
#pragma unroll
        for (int j = 0; j < 4; ++j)
          acc[i][j] = fmaf(ar[i], br[j], acc[i][j]);
    }
  }

  const int crow0 = blockIdx.y * 64 + (ty << 2);
  const int ccol  = blockIdx.x * 64 + (tx << 2);
  if (ccol < N) {
    float4 bz = *(const float4*)(bias + ccol);
#pragma unroll
    for (int i = 0; i < 4; ++i) {
      float4 o;
      o.x = acc[i][0] + bz.x;
      o.y = acc[i][1] + bz.y;
      o.z = acc[i][2] + bz.z;
      o.w = acc[i][3] + bz.w;
      *(float4*)(C + (size_t)(crow0 + i) * N + ccol) = o;
    }
  }
}

// ---------------------------------------------------------------------------
// occil[t][r] = cos((tick + t + 1) * omega_r), omega = linspace(-pi, pi, 7)
// ---------------------------------------------------------------------------
__global__ __launch_bounds__(256) void occil_kernel(const float* __restrict__ tick,
                                                    float* __restrict__ occ) {
  int t = blockIdx.x * 256 + threadIdx.x;
  if (t >= T_SEQ) return;
  float tickt = tick[0] + (float)(t + 1);
#pragma unroll
  for (int r = 0; r < NR; ++r) {
    float om = (float)(-3.14159265358979323846 + r * (3.14159265358979323846 / 3.0));
    occ[t * 8 + r] = cosf(tickt * om);
  }
  occ[t * 8 + 7] = 0.f;
}

// ---------------------------------------------------------------------------
// Pass A: per (chunk, head, dd) compute local scan end-state (y, zero init)
// and total discount products (P) for the 39 chains owned by each thread.
// ysum layout: [c][h][slot(44)][dd]; slots: fk r*4+n (0..27), fv 28+r,
// fs 35+n, Pg 39+n, Pb 43.
// ---------------------------------------------------------------------------
__global__ __launch_bounds__(64) void pass_a(
    const float* __restrict__ kqv, const float* __restrict__ p,
    const float* __restrict__ occ, const int* __restrict__ term,
    float* __restrict__ ysum) {
  const int c = blockIdx.x, h = blockIdx.y, dd = threadIdx.x;
  __shared__ float sp[CHUNK][12];
  __shared__ float socc[CHUNK][8];
  __shared__ float snt[CHUNK];
  for (int i = dd; i < CHUNK * 12; i += 64) {
    int t = i / 12, j = i - t * 12;
    sp[t][j] = p[(size_t)(c * CHUNK + t) * NP + h * 12 + j];
  }
  for (int i = dd; i < CHUNK * 8; i += 64)
    socc[i >> 3][i & 7] = occ[(size_t)c * CHUNK * 8 + i];
  for (int t = dd; t < CHUNK; t += 64)
    snt[t] = 1.f - (float)term[c * CHUNK + t];
  __syncthreads();

  float yk[NR][ETA], yv[NR], ys[ETA], Pg[ETA], Pb = 1.f;
#pragma unroll
  for (int r = 0; r < NR; ++r) {
    yv[r] = 0.f;
#pragma unroll
    for (int n = 0; n < ETA; ++n) yk[r][n] = 0.f;
  }
#pragma unroll
  for (int n = 0; n < ETA; ++n) { ys[n] = 0.f; Pg[n] = 1.f; }

  for (int t = 0; t < CHUNK; ++t) {
    const size_t base = (size_t)(c * CHUNK + t) * NKQV + h * 320 + dd;
    float kx = kqv[base];
    float vx = kqv[base + 128];
    float bx = kqv[base + 192];
    float gx = kqv[base + 256];
    float nt = snt[t];
    float rk = fmaxf(kx, 0.f);
    float sg = sigm(gx);
    float sb = sigm(bx);
    float occr[NR];
#pragma unroll
    for (int r = 0; r < NR; ++r) occr[r] = socc[t][r];
#pragma unroll
    for (int n = 0; n < ETA; ++n) {
      float rp1 = fmaxf(sp[t][n], 0.f);
      float sp3 = sigm(sp[t][8 + n]);
      float gam = sg * sp3;
      float xs  = rk * rp1 * gam;
      float dg  = (1.f - gam) * nt;
      Pg[n] *= dg;
      ys[n] = fmaf(ys[n], dg, xs);
#pragma unroll
      for (int r = 0; r < NR; ++r)
        yk[r][n] = fmaf(yk[r][n], dg, xs * occr[r]);
    }
    float vb = vx * sb;
    float db = (1.f - sb) * nt;
    Pb *= db;
#pragma unroll
    for (int r = 0; r < NR; ++r) yv[r] = fmaf(yv[r], db, vb * occr[r]);
  }

  float* o = ysum + (size_t)(c * NH + h) * 44 * 64 + dd;
#pragma unroll
  for (int r = 0; r < NR; ++r)
#pragma unroll
    for (int n = 0; n < ETA; ++n) o[(r * 4 + n) * 64] = yk[r][n];
#pragma unroll
  for (int r = 0; r < NR; ++r) o[(28 + r) * 64] = yv[r];
#pragma unroll
  for (int n = 0; n < ETA; ++n) o[(35 + n) * 64] = ys[n];
#pragma unroll
  for (int n = 0; n < ETA; ++n) o[(39 + n) * 64] = Pg[n];
  o[43 * 64] = Pb;
}

// ---------------------------------------------------------------------------
// Pass B: sequential carry propagation across chunks.
// carry[c] = state entering chunk c. carry layout: [c][h][slot(39)][dd].
// ---------------------------------------------------------------------------
__global__ __launch_bounds__(64) void pass_b(
    const float* __restrict__ ysum, const float* __restrict__ k_prev,
    const float* __restrict__ v_prev, const float* __restrict__ s_prev,
    float* __restrict__ carry) {
  const int h = blockIdx.x, dd = threadIdx.x;
  float fk[NR][ETA], fv[NR], fs[ETA];
#pragma unroll
  for (int r = 0; r < NR; ++r) {
#pragma unroll
    for (int n = 0; n < ETA; ++n)
      fk[r][n] = k_prev[(size_t)(r * NH + h) * 256 + n * 64 + dd];
    fv[r] = v_prev[(size_t)(r * NH + h) * 64 + dd];
  }
#pragma unroll
  for (int n = 0; n < ETA; ++n) fs[n] = s_prev[(size_t)h * 256 + n * 64 + dd];

  for (int c = 0; c < NCHUNK; ++c) {
    float* co = carry + (size_t)(c * NH + h) * 39 * 64 + dd;
#pragma unroll
    for (int r = 0; r < NR; ++r)
#pragma unroll
      for (int n = 0; n < ETA; ++n) co[(r * 4 + n) * 64] = fk[r][n];
#pragma unroll
    for (int r = 0; r < NR; ++r) co[(28 + r) * 64] = fv[r];
#pragma unroll
    for (int n = 0; n < ETA; ++n) co[(35 + n) * 64] = fs[n];

    const float* yo = ysum + (size_t)(c * NH + h) * 44 * 64 + dd;
    float Pg[ETA];
#pragma unroll
    for (int n = 0; n < ETA; ++n) Pg[n] = yo[(39 + n) * 64];
    float Pb = yo[43 * 64];
#pragma unroll
    for (int r = 0; r < NR; ++r) {
#pragma unroll
      for (int n = 0; n < ETA; ++n)
        fk[r][n] = fmaf(fk[r][n], Pg[n], yo[(r * 4 + n) * 64]);
      fv[r] = fmaf(fv[r], Pb, yo[(28 + r) * 64]);
    }
#pragma unroll
    for (int n = 0; n < ETA; ++n) fs[n] = fmaf(fs[n], Pg[n], yo[(35 + n) * 64]);
  }
}

// ---------------------------------------------------------------------------
// Pass C: replay each chunk with its carry-in; fuse kdq/norm/kv dots and
// emit pre-projection attention (T,512). Chunk 63 also writes final states.
// ---------------------------------------------------------------------------
__global__ __launch_bounds__(64) void pass_c(
    const float* __restrict__ kqv, const float* __restrict__ p,
    const float* __restrict__ occ, const int* __restrict__ term,
    const float* __restrict__ carry, float* __restrict__ attn,
    float* __restrict__ out, const float* __restrict__ tick) {
  const int c = blockIdx.x, h = blockIdx.y, dd = threadIdx.x;
  __shared__ float sp[CHUNK][12];
  __shared__ float socc[CHUNK][8];
  __shared__ float snt[CHUNK];
  for (int i = dd; i < CHUNK * 12; i += 64) {
    int t = i / 12, j = i - t * 12;
    sp[t][j] = p[(size_t)(c * CHUNK + t) * NP + h * 12 + j];
  }
  for (int i = dd; i < CHUNK * 8; i += 64)
    socc[i >> 3][i & 7] = occ[(size_t)c * CHUNK * 8 + i];
  for (int t = dd; t < CHUNK; t += 64)
    snt[t] = 1.f - (float)term[c * CHUNK + t];

  const float* cp = carry + (size_t)(c * NH + h) * 39 * 64 + dd;
  float fk[NR][ETA], fv[NR], fs[ETA];
#pragma unroll
  for (int r = 0; r < NR; ++r) {
#pragma unroll
    for (int n = 0; n < ETA; ++n) fk[r][n] = cp[(r * 4 + n) * 64];
    fv[r] = cp[(28 + r) * 64];
  }
#pragma unroll
  for (int n = 0; n < ETA; ++n) fs[n] = cp[(35 + n) * 64];
  __syncthreads();

  for (int t = 0; t < CHUNK; ++t) {
    const size_t base = (size_t)(c * CHUNK + t) * NKQV + h * 320 + dd;
    float kx = kqv[base];
    float qx = kqv[base + 64];
    float vx = kqv[base + 128];
    float bx = kqv[base + 192];
    float gx = kqv[base + 256];
    float nt = snt[t];
    float rk = fmaxf(kx, 0.f);
    float rq = fmaxf(qx, 0.f);
    float sg = sigm(gx);
    float sb = sigm(bx);
    float occr[NR];
#pragma unroll
    for (int r = 0; r < NR; ++r) occr[r] = socc[t][r];
    float kdqp[NR];
#pragma unroll
    for (int r = 0; r < NR; ++r) kdqp[r] = 0.f;
    float normp = 0.f;
#pragma unroll
    for (int n = 0; n < ETA; ++n) {
      float rp1 = fmaxf(sp[t][n], 0.f);
      float rp2 = fmaxf(sp[t][4 + n], 0.f);
      float sp3 = sigm(sp[t][8 + n]);
      float gam = sg * sp3;
      float xs  = rk * rp1 * gam;
      float dg  = (1.f - gam) * nt;
      float qf  = rq * rp2;
      fs[n] = fmaf(fs[n], dg, xs);
      normp = fmaf(fs[n], qf, normp);
#pragma unroll
      for (int r = 0; r < NR; ++r) {
        fk[r][n] = fmaf(fk[r][n], dg, xs * occr[r]);
        kdqp[r]  = fmaf(fk[r][n], qf, kdqp[r]);
      }
    }
    float vb = vx * sb;
    float db = (1.f - sb) * nt;
#pragma unroll
    for (int r = 0; r < NR; ++r) fv[r] = fmaf(fv[r], db, vb * occr[r]);

    // 8 butterfly sum-reductions across the 64-lane wave (result in all lanes)
    float red[8];
#pragma unroll
    for (int r = 0; r < NR; ++r) red[r] = kdqp[r];
    red[7] = normp;
#pragma unroll
    for (int i = 0; i < 8; ++i) {
      float x = red[i];
#pragma unroll
      for (int m = 1; m < 64; m <<= 1) x += __shfl_xor(x, m, 64);
      red[i] = x;
    }
    float denom = fmaf(14.f, red[7], 1e-5f);  // 2*R*norm + eps
    float kvv = 0.f;
#pragma unroll
    for (int r = 0; r < NR; ++r) kvv = fmaf(fv[r], red[r], kvv);
    attn[(size_t)(c * CHUNK + t) * 512 + h * 64 + dd] = kvv / denom;
  }

  if (c == NCHUNK - 1) {
#pragma unroll
    for (int r = 0; r < NR; ++r) {
#pragma unroll
      for (int n = 0; n < ETA; ++n)
        out[O_FK + (size_t)(r * NH + h) * 256 + n * 64 + dd] = fk[r][n];
      out[O_FV + (size_t)(r * NH + h) * 64 + dd] = fv[r];
    }
#pragma unroll
    for (int n = 0; n < ETA; ++n)
      out[O_FS + (size_t)h * 256 + n * 64 + dd] = fs[n];
    if (h == 0 && dd == 0) out[O_TICK] = tick[0] + (float)T_SEQ;
  }
}

// ---------------------------------------------------------------------------
extern "C" void kernel_launch(void* const* d_in, const int* in_sizes, int n_in,
                              void* d_out, int out_size, void* d_ws, size_t ws_size,
                              hipStream_t stream) {
  const float* inputs = (const float*)d_in[0];
  const int*   term   = (const int*)d_in[1];
  const float* k_prev = (const float*)d_in[2];
  const float* v_prev = (const float*)d_in[3];
  const float* s_prev = (const float*)d_in[4];
  const float* tick   = (const float*)d_in[5];
  const float* W_kqv  = (const float*)d_in[6];
  const float* b_kqv  = (const float*)d_in[7];
  const float* W_p    = (const float*)d_in[8];
  const float* b_p    = (const float*)d_in[9];
  const float* W_proj = (const float*)d_in[10];
  const float* b_proj = (const float*)d_in[11];
  float* out = (float*)d_out;
  float* ws  = (float*)d_ws;

  float* kqv   = ws + KQV_OFF;
  float* pbuf  = ws + P_OFF;
  float* occ   = ws + OCC_OFF;
  float* attn  = ws + ATTN_OFF;
  float* ysum  = ws + YSUM_OFF;
  float* carry = ws + CARRY_OFF;

  // 1) input projections
  gemm_bias_f32<<<dim3(NKQV / 64, T_SEQ / 64), 256, 0, stream>>>(
      inputs, W_kqv, b_kqv, kqv, T_SEQ, NKQV, DIM);
  gemm_bias_f32<<<dim3(2, T_SEQ / 64), 256, 0, stream>>>(
      inputs, W_p, b_p, pbuf, T_SEQ, NP, DIM);

  // 2) oscillation table
  occil_kernel<<<T_SEQ / 256, 256, 0, stream>>>(tick, occ);

  // 3) chunked linear scan: local pass, carry pass, replay+attend pass
  pass_a<<<dim3(NCHUNK, NH), 64, 0, stream>>>(kqv, pbuf, occ, term, ysum);
  pass_b<<<NH, 64, 0, stream>>>(ysum, k_prev, v_prev, s_prev, carry);
  pass_c<<<dim3(NCHUNK, NH), 64, 0, stream>>>(kqv, pbuf, occ, term, carry,
                                              attn, out, tick);

  // 4) output projection
  gemm_bias_f32<<<dim3(DIM / 64, T_SEQ / 64), 256, 0, stream>>>(
      attn, W_proj, b_proj, out, T_SEQ, DIM, NH * HDIM);
}

// Round 2
// 222.136 us; speedup vs baseline: 2.7280x; 2.7280x over previous
//
#include <hip/hip_runtime.h>
#include <hip/hip_bf16.h>
#include <math.h>

// Problem constants
#define T_SEQ 4096
#define DIM   1024
#define NH    8
#define HDIM  64
#define ETA   4
#define NR    7
#define NKQV  2560   // H*HD*5
#define NP_PAD 128   // p projection padded from 96 to 128 cols
#define CHUNK 64
#define NCHUNK 64    // T_SEQ / CHUNK

typedef __attribute__((ext_vector_type(8))) short bf16x8;
typedef __attribute__((ext_vector_type(4))) short short4v;
typedef __attribute__((ext_vector_type(4))) float f32x4;

// Workspace layout (float offsets). Total ~53.2 MB (< 62.9 MB used in R1).
#define ABF_OFF     0ul          // inputs bf16: 4096*1024 sh = 2,097,152 fl
#define BTKQV_OFF   2097152ul    // W_kqv^T bf16: 2560*1024 sh = 1,310,720 fl
#define BTP_OFF     3407872ul    // W_p^T bf16 (128 rows alloc): 65,536 fl
#define BTPROJ_OFF  3473408ul    // W_proj^T bf16: 1024*512 sh = 262,144 fl
#define KQVBF_OFF   3735552ul    // kqv bf16: 4096*2560 sh = 5,242,880 fl
#define PBUF_OFF    8978432ul    // p f32: 4096*128 = 524,288 fl
#define OCC_OFF     9502720ul    // occ f32: 4096*8 = 32,768 fl
#define ATTNBF_OFF  9535488ul    // attn bf16: 4096*512 sh = 1,048,576 fl
#define YSUM_OFF    10584064ul   // 64*8*44*64 = 1,441,792 fl
#define CARRY_OFF   12025856ul   // 64*8*39*64 = 1,277,952 fl

// Output layout (float offsets), concatenated in return order
#define O_ATTN 0ul
#define O_FK   4194304ul   // (7,8,256)
#define O_FV   4208640ul   // (7,8,64)
#define O_FS   4212224ul   // (8,256)
#define O_TICK 4214272ul   // (1,)

__device__ __forceinline__ float sigm(float x) { return 1.f / (1.f + __expf(-x)); }

__device__ __forceinline__ short f2bf(float f) {
  union { __hip_bfloat16 b; short s; } u;
  u.b = __float2bfloat16(f);
  return u.s;
}
__device__ __forceinline__ float bf2f(short s) {
  union { __hip_bfloat16 b; short s2; } u;
  u.s2 = s;
  return __bfloat162float(u.b);
}

__device__ __forceinline__ void gload16(const void* g, void* l) {
  __builtin_amdgcn_global_load_lds(
      (const __attribute__((address_space(1))) void*)g,
      (__attribute__((address_space(3))) void*)l, 16, 0, 0);
}

// ---------------------------------------------------------------------------
// Cast f32 -> bf16, 4 elements/thread. n must be a multiple of 4*256.
// ---------------------------------------------------------------------------
__global__ __launch_bounds__(256) void cast_f32_bf16(
    const float* __restrict__ x, short* __restrict__ y) {
  size_t i = (size_t)(blockIdx.x * 256 + threadIdx.x) * 4;
  float4 v = *(const float4*)(x + i);
  short4v o;
  o.x = f2bf(v.x); o.y = f2bf(v.y); o.z = f2bf(v.z); o.w = f2bf(v.w);
  *(short4v*)(y + i) = o;
}

// ---------------------------------------------------------------------------
// Transposing cast: W [K][N] f32 -> Bt [N][K] bf16. 32x32 tiles, block (32,8).
// ---------------------------------------------------------------------------
__global__ __launch_bounds__(256) void transpose_cast(
    const float* __restrict__ W, short* __restrict__ Bt, int K, int N) {
  __shared__ float tile[32][33];
  int n0 = blockIdx.x * 32, k0 = blockIdx.y * 32;
  int tx = threadIdx.x, ty = threadIdx.y;
  for (int i = ty; i < 32; i += 8)
    tile[i][tx] = W[(size_t)(k0 + i) * N + n0 + tx];
  __syncthreads();
  for (int i = ty; i < 32; i += 8)
    Bt[(size_t)(n0 + i) * K + k0 + tx] = f2bf(tile[tx][i]);
}

// ---------------------------------------------------------------------------
// MFMA GEMM: C[M,N] = A[M,K] @ Bt[N,K]^T + bias.  A,Bt bf16; C f32 or bf16.
// 128x128 tile, BK=32, 256 threads (4 waves 2x2), 16x16x32 MFMA, 4x4 frags.
// Requires M%128==0, N%128==0, K%32==0, Nreal%16==0. Grid 1-D, %8==0.
// m97 structure: global_load_lds(16B) staging, 2 barriers/K-step.
// ---------------------------------------------------------------------------
template <int OUT_BF16>
__global__ __launch_bounds__(256) void gemm_bt_mfma(
    const short* __restrict__ A, const short* __restrict__ Bt,
    const float* __restrict__ bias, void* __restrict__ Cout,
    int M, int N, int K, int Nreal) {
  __shared__ __align__(16) short As[128 * 32];  // [row][k] rows of 64B
  __shared__ __align__(16) short Bs[128 * 32];

  // XCD-aware bijective swizzle (gridDim.x % 8 == 0 guaranteed by caller)
  int nwg = gridDim.x;
  int cpx = nwg >> 3;
  int bid = blockIdx.x;
  int swz = (bid & 7) * cpx + (bid >> 3);
  int nbx = N >> 7;
  int bm0 = (swz / nbx) << 7;
  int bn0 = (swz % nbx) << 7;

  const int tid = threadIdx.x;
  const int w = tid >> 6, l = tid & 63;
  const int wm = w >> 1, wn = w & 1;
  const int fr = l & 15;   // fragment row/col index
  const int fq = l >> 4;   // quad

  // staging: 8 chunks of 1KB each per operand; wave w stages chunks 2w,2w+1
  const int ca = w * 2;
  short* AsC0 = &As[(ca + 0) * 512];
  short* AsC1 = &As[(ca + 1) * 512];
  short* BsC0 = &Bs[(ca + 0) * 512];
  short* BsC1 = &Bs[(ca + 1) * 512];
  const short* Ag0 = A + (size_t)(bm0 + ca * 16 + (l >> 2)) * K + (l & 3) * 8;
  const short* Ag1 = Ag0 + (size_t)16 * K;
  const short* Bg0 = Bt + (size_t)(bn0 + ca * 16 + (l >> 2)) * K + (l & 3) * 8;
  const short* Bg1 = Bg0 + (size_t)16 * K;

  const short* ArP = &As[(wm * 64 + fr) * 32 + fq * 8];
  const short* BrP = &Bs[(wn * 64 + fr) * 32 + fq * 8];

  f32x4 acc[4][4];
#pragma unroll
  for (int mi = 0; mi < 4; ++mi)
#pragma unroll
    for (int ni = 0; ni < 4; ++ni)
#pragma unroll
      for (int r = 0; r < 4; ++r) acc[mi][ni][r] = 0.f;

  for (int k0 = 0; k0 < K; k0 += 32) {
    __syncthreads();
    gload16(Ag0 + k0, AsC0);
    gload16(Ag1 + k0, AsC1);
    gload16(Bg0 + k0, BsC0);
    gload16(Bg1 + k0, BsC1);
    __syncthreads();
    bf16x8 af[4], bfv[4];
#pragma unroll
    for (int mi = 0; mi < 4; ++mi) af[mi] = *(const bf16x8*)(ArP + mi * 512);
#pragma unroll
    for (int ni = 0; ni < 4; ++ni) bfv[ni] = *(const bf16x8*)(BrP + ni * 512);
#pragma unroll
    for (int mi = 0; mi < 4; ++mi)
#pragma unroll
      for (int ni = 0; ni < 4; ++ni)
        acc[mi][ni] = __builtin_amdgcn_mfma_f32_16x16x32_bf16(
            af[mi], bfv[ni], acc[mi][ni], 0, 0, 0);
  }

  // C/D layout: col = lane&15, row = (lane>>4)*4 + reg  [m89 verified]
#pragma unroll
  for (int ni = 0; ni < 4; ++ni) {
    int col = bn0 + wn * 64 + ni * 16 + fr;
    if (col >= Nreal) continue;
    float bz = bias[col];
#pragma unroll
    for (int mi = 0; mi < 4; ++mi) {
      int row = bm0 + wm * 64 + mi * 16 + fq * 4;
#pragma unroll
      for (int r = 0; r < 4; ++r) {
        float v = acc[mi][ni][r] + bz;
        size_t off = (size_t)(row + r) * N + col;
        if (OUT_BF16)
          ((short*)Cout)[off] = f2bf(v);
        else
          ((float*)Cout)[off] = v;
      }
    }
  }
}

// ---------------------------------------------------------------------------
// occil[t][r] = cos((tick + t + 1) * omega_r), omega = linspace(-pi, pi, 7)
// ---------------------------------------------------------------------------
__global__ __launch_bounds__(256) void occil_kernel(const float* __restrict__ tick,
                                                    float* __restrict__ occ) {
  int t = blockIdx.x * 256 + threadIdx.x;
  if (t >= T_SEQ) return;
  float tickt = tick[0] + (float)(t + 1);
#pragma unroll
  for (int r = 0; r < NR; ++r) {
    float om = (float)(-3.14159265358979323846 + r * (3.14159265358979323846 / 3.0));
    occ[t * 8 + r] = cosf(tickt * om);
  }
  occ[t * 8 + 7] = 0.f;
}

// ---------------------------------------------------------------------------
// Pass A: per (chunk, head, dd) local scan end-states + discount products.
// ysum layout: [c][h][slot(44)][dd]; slots: fk r*4+n (0..27), fv 28+r,
// fs 35+n, Pg 39+n, Pb 43.
// ---------------------------------------------------------------------------
__global__ __launch_bounds__(64) void pass_a(
    const short* __restrict__ kqv, const float* __restrict__ p,
    const float* __restrict__ occ, const int* __restrict__ term,
    float* __restrict__ ysum) {
  const int c = blockIdx.x, h = blockIdx.y, dd = threadIdx.x;
  __shared__ float sp[CHUNK][12];
  __shared__ float socc[CHUNK][8];
  __shared__ float snt[CHUNK];
  for (int i = dd; i < CHUNK * 12; i += 64) {
    int t = i / 12, j = i - t * 12;
    sp[t][j] = p[(size_t)(c * CHUNK + t) * NP_PAD + h * 12 + j];
  }
  for (int i = dd; i < CHUNK * 8; i += 64)
    socc[i >> 3][i & 7] = occ[(size_t)c * CHUNK * 8 + i];
  for (int t = dd; t < CHUNK; t += 64)
    snt[t] = 1.f - (float)term[c * CHUNK + t];
  __syncthreads();

  float yk[NR][ETA], yv[NR], ys[ETA], Pg[ETA], Pb = 1.f;
#pragma unroll
  for (int r = 0; r < NR; ++r) {
    yv[r] = 0.f;
#pragma unroll
    for (int n = 0; n < ETA; ++n) yk[r][n] = 0.f;
  }
#pragma unroll
  for (int n = 0; n < ETA; ++n) { ys[n] = 0.f; Pg[n] = 1.f; }

  size_t bcur = (size_t)(c * CHUNK) * NKQV + h * 320 + dd;
  short ck = kqv[bcur], cv = kqv[bcur + 128], cbt = kqv[bcur + 192], cg = kqv[bcur + 256];
  for (int t = 0; t < CHUNK; ++t) {
    size_t bnx = bcur + (t < CHUNK - 1 ? NKQV : 0);
    short nk = kqv[bnx], nv = kqv[bnx + 128], nbt = kqv[bnx + 192], ng = kqv[bnx + 256];

    float nt = snt[t];
    float rk = fmaxf(bf2f(ck), 0.f);
    float sg = sigm(bf2f(cg));
    float sb = sigm(bf2f(cbt));
    float occr[NR];
#pragma unroll
    for (int r = 0; r < NR; ++r) occr[r] = socc[t][r];
#pragma unroll
    for (int n = 0; n < ETA; ++n) {
      float rp1 = fmaxf(sp[t][n], 0.f);
      float sp3 = sigm(sp[t][8 + n]);
      float gam = sg * sp3;
      float xs  = rk * rp1 * gam;
      float dg  = (1.f - gam) * nt;
      Pg[n] *= dg;
      ys[n] = fmaf(ys[n], dg, xs);
#pragma unroll
      for (int r = 0; r < NR; ++r)
        yk[r][n] = fmaf(yk[r][n], dg, xs * occr[r]);
    }
    float vb = bf2f(cv) * sb;
    float db = (1.f - sb) * nt;
    Pb *= db;
#pragma unroll
    for (int r = 0; r < NR; ++r) yv[r] = fmaf(yv[r], db, vb * occr[r]);

    ck = nk; cv = nv; cbt = nbt; cg = ng; bcur = bnx;
  }

  float* o = ysum + (size_t)(c * NH + h) * 44 * 64 + dd;
#pragma unroll
  for (int r = 0; r < NR; ++r)
#pragma unroll
    for (int n = 0; n < ETA; ++n) o[(r * 4 + n) * 64] = yk[r][n];
#pragma unroll
  for (int r = 0; r < NR; ++r) o[(28 + r) * 64] = yv[r];
#pragma unroll
  for (int n = 0; n < ETA; ++n) o[(35 + n) * 64] = ys[n];
#pragma unroll
  for (int n = 0; n < ETA; ++n) o[(39 + n) * 64] = Pg[n];
  o[43 * 64] = Pb;
}

// ---------------------------------------------------------------------------
// Pass B: carry propagation, one thread per chain (8*39*64 = 19968 chains).
// carry[c][h][slot(39)][dd] = state entering chunk c.
// ---------------------------------------------------------------------------
__global__ __launch_bounds__(256) void pass_b(
    const float* __restrict__ ysum, const float* __restrict__ k_prev,
    const float* __restrict__ v_prev, const float* __restrict__ s_prev,
    float* __restrict__ carry) {
  int idx = blockIdx.x * 256 + threadIdx.x;
  int dd = idx & 63;
  int slot = (idx >> 6) % 39;
  int h = idx / (39 * 64);

  int pslot;
  float f;
  if (slot < 28) {
    int r = slot >> 2, n = slot & 3;
    f = k_prev[(size_t)(r * NH + h) * 256 + n * 64 + dd];
    pslot = 39 + n;
  } else if (slot < 35) {
    int r = slot - 28;
    f = v_prev[(size_t)(r * NH + h) * 64 + dd];
    pslot = 43;
  } else {
    int n = slot - 35;
    f = s_prev[(size_t)h * 256 + n * 64 + dd];
    pslot = 39 + n;
  }
  const float* yb = ysum + (size_t)h * 44 * 64 + slot * 64 + dd;
  const float* pb = ysum + (size_t)h * 44 * 64 + pslot * 64 + dd;
  float* cb = carry + (size_t)h * 39 * 64 + slot * 64 + dd;
#pragma unroll 4
  for (int c = 0; c < NCHUNK; ++c) {
    cb[(size_t)c * NH * 39 * 64] = f;
    f = fmaf(f, pb[(size_t)c * NH * 44 * 64], yb[(size_t)c * NH * 44 * 64]);
  }
}

// ---------------------------------------------------------------------------
// Pass C: replay chunk with carry-in; fused kdq/norm/kv dots; attn out (bf16).
// Chunk 63 also writes final states + tick.
// ---------------------------------------------------------------------------
__global__ __launch_bounds__(64) void pass_c(
    const short* __restrict__ kqv, const float* __restrict__ p,
    const float* __restrict__ occ, const int* __restrict__ term,
    const float* __restrict__ carry, short* __restrict__ attn,
    float* __restrict__ out, const float* __restrict__ tick) {
  const int c = blockIdx.x, h = blockIdx.y, dd = threadIdx.x;
  __shared__ float sp[CHUNK][12];
  __shared__ float socc[CHUNK][8];
  __shared__ float snt[CHUNK];
  for (int i = dd; i < CHUNK * 12; i += 64) {
    int t = i / 12, j = i - t * 12;
    sp[t][j] = p[(size_t)(c * CHUNK + t) * NP_PAD + h * 12 + j];
  }
  for (int i = dd; i < CHUNK * 8; i += 64)
    socc[i >> 3][i & 7] = occ[(size_t)c * CHUNK * 8 + i];
  for (int t = dd; t < CHUNK; t += 64)
    snt[t] = 1.f - (float)term[c * CHUNK + t];

  const float* cp = carry + (size_t)(c * NH + h) * 39 * 64 + dd;
  float fk[NR][ETA], fv[NR], fs[ETA];
#pragma unroll
  for (int r = 0; r < NR; ++r) {
#pragma unroll
    for (int n = 0; n < ETA; ++n) fk[r][n] = cp[(r * 4 + n) * 64];
    fv[r] = cp[(28 + r) * 64];
  }
#pragma unroll
  for (int n = 0; n < ETA; ++n) fs[n] = cp[(35 + n) * 64];
  __syncthreads();

  size_t bcur = (size_t)(c * CHUNK) * NKQV + h * 320 + dd;
  short ck = kqv[bcur], cq = kqv[bcur + 64], cv = kqv[bcur + 128],
        cbt = kqv[bcur + 192], cg = kqv[bcur + 256];
  for (int t = 0; t < CHUNK; ++t) {
    size_t bnx = bcur + (t < CHUNK - 1 ? NKQV : 0);
    short nk = kqv[bnx], nq = kqv[bnx + 64], nv = kqv[bnx + 128],
          nbt = kqv[bnx + 192], ng = kqv[bnx + 256];

    float nt = snt[t];
    float rk = fmaxf(bf2f(ck), 0.f);
    float rq = fmaxf(bf2f(cq), 0.f);
    float sg = sigm(bf2f(cg));
    float sb = sigm(bf2f(cbt));
    float occr[NR];
#pragma unroll
    for (int r = 0; r < NR; ++r) occr[r] = socc[t][r];
    float kdqp[NR];
#pragma unroll
    for (int r = 0; r < NR; ++r) kdqp[r] = 0.f;
    float normp = 0.f;
#pragma unroll
    for (int n = 0; n < ETA; ++n) {
      float rp1 = fmaxf(sp[t][n], 0.f);
      float rp2 = fmaxf(sp[t][4 + n], 0.f);
      float sp3 = sigm(sp[t][8 + n]);
      float gam = sg * sp3;
      float xs  = rk * rp1 * gam;
      float dg  = (1.f - gam) * nt;
      float qf  = rq * rp2;
      fs[n] = fmaf(fs[n], dg, xs);
      normp = fmaf(fs[n], qf, normp);
#pragma unroll
      for (int r = 0; r < NR; ++r) {
        fk[r][n] = fmaf(fk[r][n], dg, xs * occr[r]);
        kdqp[r]  = fmaf(fk[r][n], qf, kdqp[r]);
      }
    }
    float vb = bf2f(cv) * sb;
    float db = (1.f - sb) * nt;
#pragma unroll
    for (int r = 0; r < NR; ++r) fv[r] = fmaf(fv[r], db, vb * occr[r]);

    // 8 butterfly sum-reductions across the 64-lane wave
    float red[8];
#pragma unroll
    for (int r = 0; r < NR; ++r) red[r] = kdqp[r];
    red[7] = normp;
#pragma unroll
    for (int i = 0; i < 8; ++i) {
      float x = red[i];
#pragma unroll
      for (int m = 1; m < 64; m <<= 1) x += __shfl_xor(x, m, 64);
      red[i] = x;
    }
    float denom = fmaf(14.f, red[7], 1e-5f);  // 2*R*norm + eps
    float kvv = 0.f;
#pragma unroll
    for (int r = 0; r < NR; ++r) kvv = fmaf(fv[r], red[r], kvv);
    attn[(size_t)(c * CHUNK + t) * 512 + h * 64 + dd] = f2bf(kvv / denom);

    ck = nk; cq = nq; cv = nv; cbt = nbt; cg = ng; bcur = bnx;
  }

  if (c == NCHUNK - 1) {
#pragma unroll
    for (int r = 0; r < NR; ++r) {
#pragma unroll
      for (int n = 0; n < ETA; ++n)
        out[O_FK + (size_t)(r * NH + h) * 256 + n * 64 + dd] = fk[r][n];
      out[O_FV + (size_t)(r * NH + h) * 64 + dd] = fv[r];
    }
#pragma unroll
    for (int n = 0; n < ETA; ++n)
      out[O_FS + (size_t)h * 256 + n * 64 + dd] = fs[n];
    if (h == 0 && dd == 0) out[O_TICK] = tick[0] + (float)T_SEQ;
  }
}

// ---------------------------------------------------------------------------
extern "C" void kernel_launch(void* const* d_in, const int* in_sizes, int n_in,
                              void* d_out, int out_size, void* d_ws, size_t ws_size,
                              hipStream_t stream) {
  const float* inputs = (const float*)d_in[0];
  const int*   term   = (const int*)d_in[1];
  const float* k_prev = (const float*)d_in[2];
  const float* v_prev = (const float*)d_in[3];
  const float* s_prev = (const float*)d_in[4];
  const float* tick   = (const float*)d_in[5];
  const float* W_kqv  = (const float*)d_in[6];
  const float* b_kqv  = (const float*)d_in[7];
  const float* W_p    = (const float*)d_in[8];
  const float* b_p    = (const float*)d_in[9];
  const float* W_proj = (const float*)d_in[10];
  const float* b_proj = (const float*)d_in[11];
  float* out = (float*)d_out;
  float* ws  = (float*)d_ws;

  short* Abf    = (short*)(ws + ABF_OFF);
  short* BtKqv  = (short*)(ws + BTKQV_OFF);
  short* BtP    = (short*)(ws + BTP_OFF);
  short* BtProj = (short*)(ws + BTPROJ_OFF);
  short* kqvbf  = (short*)(ws + KQVBF_OFF);
  float* pbuf   = ws + PBUF_OFF;
  float* occ    = ws + OCC_OFF;
  short* attnbf = (short*)(ws + ATTNBF_OFF);
  float* ysum   = ws + YSUM_OFF;
  float* carry  = ws + CARRY_OFF;

  // 0) casts and weight transposes (bf16)
  cast_f32_bf16<<<4096, 256, 0, stream>>>(inputs, Abf);  // 4096*1024
  transpose_cast<<<dim3(80, 32), dim3(32, 8), 0, stream>>>(W_kqv, BtKqv, 1024, 2560);
  transpose_cast<<<dim3(3, 32), dim3(32, 8), 0, stream>>>(W_p, BtP, 1024, 96);
  transpose_cast<<<dim3(32, 16), dim3(32, 8), 0, stream>>>(W_proj, BtProj, 512, 1024);

  // 1) oscillation table
  occil_kernel<<<16, 256, 0, stream>>>(tick, occ);

  // 2) input projections (MFMA)
  gemm_bt_mfma<1><<<640, 256, 0, stream>>>(Abf, BtKqv, b_kqv, kqvbf,
                                           T_SEQ, NKQV, DIM, NKQV);
  gemm_bt_mfma<0><<<32, 256, 0, stream>>>(Abf, BtP, b_p, pbuf,
                                          T_SEQ, NP_PAD, DIM, 96);

  // 3) chunked linear scan
  pass_a<<<dim3(NCHUNK, NH), 64, 0, stream>>>(kqvbf, pbuf, occ, term, ysum);
  pass_b<<<78, 256, 0, stream>>>(ysum, k_prev, v_prev, s_prev, carry);
  pass_c<<<dim3(NCHUNK, NH), 64, 0, stream>>>(kqvbf, pbuf, occ, term, carry,
                                              attnbf, out, tick);

  // 4) output projection (MFMA, f32 out)
  gemm_bt_mfma<0><<<256, 256, 0, stream>>>(attnbf, BtProj, b_proj, out,
                                           T_SEQ, DIM, NH * HDIM, DIM);
}

// Round 3
// 191.534 us; speedup vs baseline: 3.1638x; 1.1598x over previous
//
#include <hip/hip_runtime.h>
#include <hip/hip_bf16.h>
#include <math.h>

// Problem constants
#define T_SEQ 4096
#define DIM   1024
#define NH    8
#define HDIM  64
#define ETA   4
#define NR    7
#define NKQV  2560   // H*HD*5
#define NP_PAD 128   // p projection padded from 96 to 128 cols
#define CHUNK 16
#define NCHUNK 256   // T_SEQ / CHUNK

typedef __attribute__((ext_vector_type(8))) short bf16x8;
typedef __attribute__((ext_vector_type(4))) short short4v;
typedef __attribute__((ext_vector_type(4))) float f32x4;

// Workspace layout (float offsets). Total 12,877,824 fl = 51.5 MB.
// Permanent region:
#define KQVBF_OFF   0ul          // kqv bf16: 4096*2560 sh = 5,242,880 fl
#define PBUF_OFF    5242880ul    // p f32: 4096*128 = 524,288 fl
#define OCC_OFF     5767168ul    // occ f32: 4096*8 = 32,768 fl
#define BTPROJ_OFF  5799936ul    // W_proj^T bf16: 1024*512 sh = 262,144 fl
#define ATTNBF_OFF  6062080ul    // attn bf16: 4096*512 sh = 1,048,576 fl
// Transient A (dead after the input GEMMs):
#define ABF_OFF     7110656ul    // inputs bf16: 2,097,152 fl
#define BTKQV_OFF   9207808ul    // W_kqv^T bf16: 1,310,720 fl
#define BTP_OFF     10518528ul   // W_p^T bf16: 65,536 fl
// Transient B (written by pass_a, after transient A is dead; carry in-place):
#define YSUM_OFF    7110656ul    // 256*8*44*64 = 5,767,168 fl

// Output layout (float offsets), concatenated in return order
#define O_ATTN 0ul
#define O_FK   4194304ul   // (7,8,256)
#define O_FV   4208640ul   // (7,8,64)
#define O_FS   4212224ul   // (8,256)
#define O_TICK 4214272ul   // (1,)

__device__ __forceinline__ float sigm(float x) { return 1.f / (1.f + __expf(-x)); }

__device__ __forceinline__ short f2bf(float f) {
  union { __hip_bfloat16 b; short s; } u;
  u.b = __float2bfloat16(f);
  return u.s;
}
__device__ __forceinline__ float bf2f(short s) {
  union { __hip_bfloat16 b; short s2; } u;
  u.s2 = s;
  return __bfloat162float(u.b);
}

__device__ __forceinline__ void gload16(const void* g, void* l) {
  __builtin_amdgcn_global_load_lds(
      (const __attribute__((address_space(1))) void*)g,
      (__attribute__((address_space(3))) void*)l, 16, 0, 0);
}

// ---------------------------------------------------------------------------
// Cast f32 -> bf16, 4 elements/thread.
// ---------------------------------------------------------------------------
__global__ __launch_bounds__(256) void cast_f32_bf16(
    const float* __restrict__ x, short* __restrict__ y) {
  size_t i = (size_t)(blockIdx.x * 256 + threadIdx.x) * 4;
  float4 v = *(const float4*)(x + i);
  short4v o;
  o.x = f2bf(v.x); o.y = f2bf(v.y); o.z = f2bf(v.z); o.w = f2bf(v.w);
  *(short4v*)(y + i) = o;
}

// ---------------------------------------------------------------------------
// Transposing cast: W [K][N] f32 -> Bt [N][K] bf16. 32x32 tiles, block (32,8).
// ---------------------------------------------------------------------------
__global__ __launch_bounds__(256) void transpose_cast(
    const float* __restrict__ W, short* __restrict__ Bt, int K, int N) {
  __shared__ float tile[32][33];
  int n0 = blockIdx.x * 32, k0 = blockIdx.y * 32;
  int tx = threadIdx.x, ty = threadIdx.y;
  for (int i = ty; i < 32; i += 8)
    tile[i][tx] = W[(size_t)(k0 + i) * N + n0 + tx];
  __syncthreads();
  for (int i = ty; i < 32; i += 8)
    Bt[(size_t)(n0 + i) * K + k0 + tx] = f2bf(tile[tx][i]);
}

// ---------------------------------------------------------------------------
// MFMA GEMM: C[M,N] = A[M,K] @ Bt[N,K]^T + bias.  A,Bt bf16; C f32 or bf16.
// 128x128 tile, BK=32, 256 threads (4 waves 2x2), 16x16x32 MFMA, 4x4 frags.
// ---------------------------------------------------------------------------
template <int OUT_BF16>
__global__ __launch_bounds__(256) void gemm_bt_mfma(
    const short* __restrict__ A, const short* __restrict__ Bt,
    const float* __restrict__ bias, void* __restrict__ Cout,
    int M, int N, int K, int Nreal) {
  __shared__ __align__(16) short As[128 * 32];  // [row][k] rows of 64B
  __shared__ __align__(16) short Bs[128 * 32];

  // XCD-aware bijective swizzle (gridDim.x % 8 == 0 guaranteed by caller)
  int nwg = gridDim.x;
  int cpx = nwg >> 3;
  int bid = blockIdx.x;
  int swz = (bid & 7) * cpx + (bid >> 3);
  int nbx = N >> 7;
  int bm0 = (swz / nbx) << 7;
  int bn0 = (swz % nbx) << 7;

  const int tid = threadIdx.x;
  const int w = tid >> 6, l = tid & 63;
  const int wm = w >> 1, wn = w & 1;
  const int fr = l & 15;
  const int fq = l >> 4;

  const int ca = w * 2;
  short* AsC0 = &As[(ca + 0) * 512];
  short* AsC1 = &As[(ca + 1) * 512];
  short* BsC0 = &Bs[(ca + 0) * 512];
  short* BsC1 = &Bs[(ca + 1) * 512];
  const short* Ag0 = A + (size_t)(bm0 + ca * 16 + (l >> 2)) * K + (l & 3) * 8;
  const short* Ag1 = Ag0 + (size_t)16 * K;
  const short* Bg0 = Bt + (size_t)(bn0 + ca * 16 + (l >> 2)) * K + (l & 3) * 8;
  const short* Bg1 = Bg0 + (size_t)16 * K;

  const short* ArP = &As[(wm * 64 + fr) * 32 + fq * 8];
  const short* BrP = &Bs[(wn * 64 + fr) * 32 + fq * 8];

  f32x4 acc[4][4];
#pragma unroll
  for (int mi = 0; mi < 4; ++mi)
#pragma unroll
    for (int ni = 0; ni < 4; ++ni)
#pragma unroll
      for (int r = 0; r < 4; ++r) acc[mi][ni][r] = 0.f;

  for (int k0 = 0; k0 < K; k0 += 32) {
    __syncthreads();
    gload16(Ag0 + k0, AsC0);
    gload16(Ag1 + k0, AsC1);
    gload16(Bg0 + k0, BsC0);
    gload16(Bg1 + k0, BsC1);
    __syncthreads();
    bf16x8 af[4], bfv[4];
#pragma unroll
    for (int mi = 0; mi < 4; ++mi) af[mi] = *(const bf16x8*)(ArP + mi * 512);
#pragma unroll
    for (int ni = 0; ni < 4; ++ni) bfv[ni] = *(const bf16x8*)(BrP + ni * 512);
#pragma unroll
    for (int mi = 0; mi < 4; ++mi)
#pragma unroll
      for (int ni = 0; ni < 4; ++ni)
        acc[mi][ni] = __builtin_amdgcn_mfma_f32_16x16x32_bf16(
            af[mi], bfv[ni], acc[mi][ni], 0, 0, 0);
  }

  // C/D layout: col = lane&15, row = (lane>>4)*4 + reg  [m89 verified]
#pragma unroll
  for (int ni = 0; ni < 4; ++ni) {
    int col = bn0 + wn * 64 + ni * 16 + fr;
    if (col >= Nreal) continue;
    float bz = bias[col];
#pragma unroll
    for (int mi = 0; mi < 4; ++mi) {
      int row = bm0 + wm * 64 + mi * 16 + fq * 4;
#pragma unroll
      for (int r = 0; r < 4; ++r) {
        float v = acc[mi][ni][r] + bz;
        size_t off = (size_t)(row + r) * N + col;
        if (OUT_BF16)
          ((short*)Cout)[off] = f2bf(v);
        else
          ((float*)Cout)[off] = v;
      }
    }
  }
}

// ---------------------------------------------------------------------------
// occil[t][r] = cos((tick + t + 1) * omega_r), omega = linspace(-pi, pi, 7)
// ---------------------------------------------------------------------------
__global__ __launch_bounds__(256) void occil_kernel(const float* __restrict__ tick,
                                                    float* __restrict__ occ) {
  int t = blockIdx.x * 256 + threadIdx.x;
  if (t >= T_SEQ) return;
  float tickt = tick[0] + (float)(t + 1);
#pragma unroll
  for (int r = 0; r < NR; ++r) {
    float om = (float)(-3.14159265358979323846 + r * (3.14159265358979323846 / 3.0));
    occ[t * 8 + r] = cosf(tickt * om);
  }
  occ[t * 8 + 7] = 0.f;
}

// ---------------------------------------------------------------------------
// Pass A: per (chunk, head, dd) local scan end-states + discount products.
// ysum layout: [c][h][slot(44)][dd]; slots: fk r*4+n (0..27), fv 28+r,
// fs 35+n, Pg 39+n, Pb 43.
// ---------------------------------------------------------------------------
__global__ __launch_bounds__(64) void pass_a(
    const short* __restrict__ kqv, const float* __restrict__ p,
    const float* __restrict__ occ, const int* __restrict__ term,
    float* __restrict__ ysum) {
  const int c = blockIdx.x, h = blockIdx.y, dd = threadIdx.x;
  __shared__ float sp[CHUNK][12];
  __shared__ float socc[CHUNK][8];
  __shared__ float snt[CHUNK];
  for (int i = dd; i < CHUNK * 12; i += 64) {
    int t = i / 12, j = i - t * 12;
    sp[t][j] = p[(size_t)(c * CHUNK + t) * NP_PAD + h * 12 + j];
  }
  for (int i = dd; i < CHUNK * 8; i += 64)
    socc[i >> 3][i & 7] = occ[(size_t)c * CHUNK * 8 + i];
  for (int t = dd; t < CHUNK; t += 64)
    snt[t] = 1.f - (float)term[c * CHUNK + t];
  __syncthreads();

  float yk[NR][ETA], yv[NR], ys[ETA], Pg[ETA], Pb = 1.f;
#pragma unroll
  for (int r = 0; r < NR; ++r) {
    yv[r] = 0.f;
#pragma unroll
    for (int n = 0; n < ETA; ++n) yk[r][n] = 0.f;
  }
#pragma unroll
  for (int n = 0; n < ETA; ++n) { ys[n] = 0.f; Pg[n] = 1.f; }

  size_t bcur = (size_t)(c * CHUNK) * NKQV + h * 320 + dd;
  short ck = kqv[bcur], cv = kqv[bcur + 128], cbt = kqv[bcur + 192], cg = kqv[bcur + 256];
  for (int t = 0; t < CHUNK; ++t) {
    size_t bnx = bcur + (t < CHUNK - 1 ? NKQV : 0);
    short nk = kqv[bnx], nv = kqv[bnx + 128], nbt = kqv[bnx + 192], ng = kqv[bnx + 256];

    float nt = snt[t];
    float rk = fmaxf(bf2f(ck), 0.f);
    float sg = sigm(bf2f(cg));
    float sb = sigm(bf2f(cbt));
    float occr[NR];
#pragma unroll
    for (int r = 0; r < NR; ++r) occr[r] = socc[t][r];
#pragma unroll
    for (int n = 0; n < ETA; ++n) {
      float rp1 = fmaxf(sp[t][n], 0.f);
      float sp3 = sigm(sp[t][8 + n]);
      float gam = sg * sp3;
      float xs  = rk * rp1 * gam;
      float dg  = (1.f - gam) * nt;
      Pg[n] *= dg;
      ys[n] = fmaf(ys[n], dg, xs);
#pragma unroll
      for (int r = 0; r < NR; ++r)
        yk[r][n] = fmaf(yk[r][n], dg, xs * occr[r]);
    }
    float vb = bf2f(cv) * sb;
    float db = (1.f - sb) * nt;
    Pb *= db;
#pragma unroll
    for (int r = 0; r < NR; ++r) yv[r] = fmaf(yv[r], db, vb * occr[r]);

    ck = nk; cv = nv; cbt = nbt; cg = ng; bcur = bnx;
  }

  float* o = ysum + (size_t)(c * NH + h) * 44 * 64 + dd;
#pragma unroll
  for (int r = 0; r < NR; ++r)
#pragma unroll
    for (int n = 0; n < ETA; ++n) o[(r * 4 + n) * 64] = yk[r][n];
#pragma unroll
  for (int r = 0; r < NR; ++r) o[(28 + r) * 64] = yv[r];
#pragma unroll
  for (int n = 0; n < ETA; ++n) o[(35 + n) * 64] = ys[n];
#pragma unroll
  for (int n = 0; n < ETA; ++n) o[(39 + n) * 64] = Pg[n];
  o[43 * 64] = Pb;
}

// ---------------------------------------------------------------------------
// Pass B: carry propagation IN-PLACE in ysum: y-slot s of chunk c is
// overwritten with the carry-in state for chunk c (read y before write).
// P-slots 39..43 are read-only. One thread per chain (8*39*64 = 19968).
// ---------------------------------------------------------------------------
__global__ __launch_bounds__(256) void pass_b(
    float* __restrict__ ysum, const float* __restrict__ k_prev,
    const float* __restrict__ v_prev, const float* __restrict__ s_prev) {
  int idx = blockIdx.x * 256 + threadIdx.x;
  int dd = idx & 63;
  int slot = (idx >> 6) % 39;
  int h = idx / (39 * 64);

  int pslot;
  float f;
  if (slot < 28) {
    int r = slot >> 2, n = slot & 3;
    f = k_prev[(size_t)(r * NH + h) * 256 + n * 64 + dd];
    pslot = 39 + n;
  } else if (slot < 35) {
    int r = slot - 28;
    f = v_prev[(size_t)(r * NH + h) * 64 + dd];
    pslot = 43;
  } else {
    int n = slot - 35;
    f = s_prev[(size_t)h * 256 + n * 64 + dd];
    pslot = 39 + n;
  }
  float* yb = ysum + (size_t)h * 2816 + slot * 64 + dd;   // 44*64 = 2816
  const float* pb = ysum + (size_t)h * 2816 + pslot * 64 + dd;
#pragma unroll 4
  for (int c = 0; c < NCHUNK; ++c) {
    size_t o = (size_t)c * (NH * 2816);
    float y = yb[o];
    float pp = pb[o];
    yb[o] = f;              // overwrite y with carry-in (read y first!)
    f = fmaf(f, pp, y);
  }
}

// ---------------------------------------------------------------------------
// Pass C: replay chunk with carry-in (from in-place ysum, slots 0..38);
// fused kdq/norm/kv dots; attn out (bf16). Last chunk writes final states.
// ---------------------------------------------------------------------------
__global__ __launch_bounds__(64) void pass_c(
    const short* __restrict__ kqv, const float* __restrict__ p,
    const float* __restrict__ occ, const int* __restrict__ term,
    const float* __restrict__ carry, short* __restrict__ attn,
    float* __restrict__ out, const float* __restrict__ tick) {
  const int c = blockIdx.x, h = blockIdx.y, dd = threadIdx.x;
  __shared__ float sp[CHUNK][12];
  __shared__ float socc[CHUNK][8];
  __shared__ float snt[CHUNK];
  for (int i = dd; i < CHUNK * 12; i += 64) {
    int t = i / 12, j = i - t * 12;
    sp[t][j] = p[(size_t)(c * CHUNK + t) * NP_PAD + h * 12 + j];
  }
  for (int i = dd; i < CHUNK * 8; i += 64)
    socc[i >> 3][i & 7] = occ[(size_t)c * CHUNK * 8 + i];
  for (int t = dd; t < CHUNK; t += 64)
    snt[t] = 1.f - (float)term[c * CHUNK + t];

  const float* cp = carry + (size_t)(c * NH + h) * 2816 + dd;
  float fk[NR][ETA], fv[NR], fs[ETA];
#pragma unroll
  for (int r = 0; r < NR; ++r) {
#pragma unroll
    for (int n = 0; n < ETA; ++n) fk[r][n] = cp[(r * 4 + n) * 64];
    fv[r] = cp[(28 + r) * 64];
  }
#pragma unroll
  for (int n = 0; n < ETA; ++n) fs[n] = cp[(35 + n) * 64];
  __syncthreads();

  size_t bcur = (size_t)(c * CHUNK) * NKQV + h * 320 + dd;
  short ck = kqv[bcur], cq = kqv[bcur + 64], cv = kqv[bcur + 128],
        cbt = kqv[bcur + 192], cg = kqv[bcur + 256];
  for (int t = 0; t < CHUNK; ++t) {
    size_t bnx = bcur + (t < CHUNK - 1 ? NKQV : 0);
    short nk = kqv[bnx], nq = kqv[bnx + 64], nv = kqv[bnx + 128],
          nbt = kqv[bnx + 192], ng = kqv[bnx + 256];

    float nt = snt[t];
    float rk = fmaxf(bf2f(ck), 0.f);
    float rq = fmaxf(bf2f(cq), 0.f);
    float sg = sigm(bf2f(cg));
    float sb = sigm(bf2f(cbt));
    float occr[NR];
#pragma unroll
    for (int r = 0; r < NR; ++r) occr[r] = socc[t][r];
    float kdqp[NR];
#pragma unroll
    for (int r = 0; r < NR; ++r) kdqp[r] = 0.f;
    float normp = 0.f;
#pragma unroll
    for (int n = 0; n < ETA; ++n) {
      float rp1 = fmaxf(sp[t][n], 0.f);
      float rp2 = fmaxf(sp[t][4 + n], 0.f);
      float sp3 = sigm(sp[t][8 + n]);
      float gam = sg * sp3;
      float xs  = rk * rp1 * gam;
      float dg  = (1.f - gam) * nt;
      float qf  = rq * rp2;
      fs[n] = fmaf(fs[n], dg, xs);
      normp = fmaf(fs[n], qf, normp);
#pragma unroll
      for (int r = 0; r < NR; ++r) {
        fk[r][n] = fmaf(fk[r][n], dg, xs * occr[r]);
        kdqp[r]  = fmaf(fk[r][n], qf, kdqp[r]);
      }
    }
    float vb = bf2f(cv) * sb;
    float db = (1.f - sb) * nt;
#pragma unroll
    for (int r = 0; r < NR; ++r) fv[r] = fmaf(fv[r], db, vb * occr[r]);

    // 8 butterfly sum-reductions across the 64-lane wave
    float red[8];
#pragma unroll
    for (int r = 0; r < NR; ++r) red[r] = kdqp[r];
    red[7] = normp;
#pragma unroll
    for (int i = 0; i < 8; ++i) {
      float x = red[i];
#pragma unroll
      for (int m = 1; m < 64; m <<= 1) x += __shfl_xor(x, m, 64);
      red[i] = x;
    }
    float denom = fmaf(14.f, red[7], 1e-5f);  // 2*R*norm + eps
    float kvv = 0.f;
#pragma unroll
    for (int r = 0; r < NR; ++r) kvv = fmaf(fv[r], red[r], kvv);
    attn[(size_t)(c * CHUNK + t) * 512 + h * 64 + dd] = f2bf(kvv / denom);

    ck = nk; cq = nq; cv = nv; cbt = nbt; cg = ng; bcur = bnx;
  }

  if (c == NCHUNK - 1) {
#pragma unroll
    for (int r = 0; r < NR; ++r) {
#pragma unroll
      for (int n = 0; n < ETA; ++n)
        out[O_FK + (size_t)(r * NH + h) * 256 + n * 64 + dd] = fk[r][n];
      out[O_FV + (size_t)(r * NH + h) * 64 + dd] = fv[r];
    }
#pragma unroll
    for (int n = 0; n < ETA; ++n)
      out[O_FS + (size_t)h * 256 + n * 64 + dd] = fs[n];
    if (h == 0 && dd == 0) out[O_TICK] = tick[0] + (float)T_SEQ;
  }
}

// ---------------------------------------------------------------------------
extern "C" void kernel_launch(void* const* d_in, const int* in_sizes, int n_in,
                              void* d_out, int out_size, void* d_ws, size_t ws_size,
                              hipStream_t stream) {
  const float* inputs = (const float*)d_in[0];
  const int*   term   = (const int*)d_in[1];
  const float* k_prev = (const float*)d_in[2];
  const float* v_prev = (const float*)d_in[3];
  const float* s_prev = (const float*)d_in[4];
  const float* tick   = (const float*)d_in[5];
  const float* W_kqv  = (const float*)d_in[6];
  const float* b_kqv  = (const float*)d_in[7];
  const float* W_p    = (const float*)d_in[8];
  const float* b_p    = (const float*)d_in[9];
  const float* W_proj = (const float*)d_in[10];
  const float* b_proj = (const float*)d_in[11];
  float* out = (float*)d_out;
  float* ws  = (float*)d_ws;

  short* kqvbf  = (short*)(ws + KQVBF_OFF);
  float* pbuf   = ws + PBUF_OFF;
  float* occ    = ws + OCC_OFF;
  short* BtProj = (short*)(ws + BTPROJ_OFF);
  short* attnbf = (short*)(ws + ATTNBF_OFF);
  short* Abf    = (short*)(ws + ABF_OFF);
  short* BtKqv  = (short*)(ws + BTKQV_OFF);
  short* BtP    = (short*)(ws + BTP_OFF);
  float* ysum   = ws + YSUM_OFF;   // overlays Abf/BtKqv/BtP after GEMMs

  // 0) casts and weight transposes (bf16)
  cast_f32_bf16<<<4096, 256, 0, stream>>>(inputs, Abf);
  transpose_cast<<<dim3(80, 32), dim3(32, 8), 0, stream>>>(W_kqv, BtKqv, 1024, 2560);
  transpose_cast<<<dim3(3, 32), dim3(32, 8), 0, stream>>>(W_p, BtP, 1024, 96);
  transpose_cast<<<dim3(32, 16), dim3(32, 8), 0, stream>>>(W_proj, BtProj, 512, 1024);

  // 1) oscillation table
  occil_kernel<<<16, 256, 0, stream>>>(tick, occ);

  // 2) input projections (MFMA)
  gemm_bt_mfma<1><<<640, 256, 0, stream>>>(Abf, BtKqv, b_kqv, kqvbf,
                                           T_SEQ, NKQV, DIM, NKQV);
  gemm_bt_mfma<0><<<32, 256, 0, stream>>>(Abf, BtP, b_p, pbuf,
                                          T_SEQ, NP_PAD, DIM, 96);

  // 3) chunked linear scan (transient-A region now dead; ysum overlays it)
  pass_a<<<dim3(NCHUNK, NH), 64, 0, stream>>>(kqvbf, pbuf, occ, term, ysum);
  pass_b<<<78, 256, 0, stream>>>(ysum, k_prev, v_prev, s_prev);
  pass_c<<<dim3(NCHUNK, NH), 64, 0, stream>>>(kqvbf, pbuf, occ, term, ysum,
                                              attnbf, out, tick);

  // 4) output projection (MFMA, f32 out)
  gemm_bt_mfma<0><<<256, 256, 0, stream>>>(attnbf, BtProj, b_proj, out,
                                           T_SEQ, DIM, NH * HDIM, DIM);
}

// Round 4
// 164.396 us; speedup vs baseline: 3.6861x; 1.1651x over previous
//
#include <hip/hip_runtime.h>
#include <hip/hip_bf16.h>
#include <math.h>

// Problem constants
#define T_SEQ 4096
#define DIM   1024
#define NH    8
#define HDIM  64
#define ETA   4
#define NR    7
#define NKQVC 2688   // combined: 2560 kqv + 96 p + 32 pad
#define CHUNK 16
#define NCHUNK 256   // T_SEQ / CHUNK

typedef __attribute__((ext_vector_type(8))) short bf16x8;
typedef __attribute__((ext_vector_type(4))) short short4v;
typedef __attribute__((ext_vector_type(4))) float f32x4;

// Workspace layout (float offsets). Total 12,618,496 fl = 50.5 MB.
// Permanent:
#define KQVC_OFF    0ul          // combined kqv+p bf16: 4096*2688 sh = 5,505,024 fl
#define OCC_OFF     5505024ul    // occ f32: 4096*8 = 32,768 fl
#define BTPROJ_OFF  5537792ul    // W_proj^T bf16: 1024*512 sh = 262,144 fl
#define ATTNBF_OFF  5799936ul    // attn bf16: 4096*512 sh = 1,048,576 fl
#define BIASC_OFF   6848512ul    // concat bias f32: 2,816 fl
// Transient A (dead after input GEMM):
#define ABF_OFF     6851328ul    // inputs bf16: 2,097,152 fl
#define BTCAT_OFF   8948480ul    // [2688][1024] bf16 = 1,376,256 fl
// Transient B (overlays transient A after GEMM; carry in-place):
#define YSUM_OFF    6851328ul    // 256*8*44*64 = 5,767,168 fl

// Output layout (float offsets), concatenated in return order
#define O_ATTN 0ul
#define O_FK   4194304ul   // (7,8,256)
#define O_FV   4208640ul   // (7,8,64)
#define O_FS   4212224ul   // (8,256)
#define O_TICK 4214272ul   // (1,)

__device__ __forceinline__ float sigm(float x) { return 1.f / (1.f + __expf(-x)); }

__device__ __forceinline__ short f2bf(float f) {
  union { __hip_bfloat16 b; short s; } u;
  u.b = __float2bfloat16(f);
  return u.s;
}
__device__ __forceinline__ float bf2f(short s) {
  union { __hip_bfloat16 b; short s2; } u;
  u.s2 = s;
  return __bfloat162float(u.b);
}

__device__ __forceinline__ void gload16(const void* g, void* l) {
  __builtin_amdgcn_global_load_lds(
      (const __attribute__((address_space(1))) void*)g,
      (__attribute__((address_space(3))) void*)l, 16, 0, 0);
}

// ---------------------------------------------------------------------------
// Cast f32 -> bf16, 4 elements/thread.
// ---------------------------------------------------------------------------
__global__ __launch_bounds__(256) void cast_f32_bf16(
    const float* __restrict__ x, short* __restrict__ y) {
  size_t i = (size_t)(blockIdx.x * 256 + threadIdx.x) * 4;
  float4 v = *(const float4*)(x + i);
  short4v o;
  o.x = f2bf(v.x); o.y = f2bf(v.y); o.z = f2bf(v.z); o.w = f2bf(v.w);
  *(short4v*)(y + i) = o;
}

// ---------------------------------------------------------------------------
// Transposing cast: W [K][N] f32 -> Bt [N][K] bf16. 32x32 tiles, block (32,8).
// ---------------------------------------------------------------------------
__global__ __launch_bounds__(256) void transpose_cast(
    const float* __restrict__ W, short* __restrict__ Bt, int K, int N) {
  __shared__ float tile[32][33];
  int n0 = blockIdx.x * 32, k0 = blockIdx.y * 32;
  int tx = threadIdx.x, ty = threadIdx.y;
  for (int i = ty; i < 32; i += 8)
    tile[i][tx] = W[(size_t)(k0 + i) * N + n0 + tx];
  __syncthreads();
  for (int i = ty; i < 32; i += 8)
    Bt[(size_t)(n0 + i) * K + k0 + tx] = f2bf(tile[tx][i]);
}

// ---------------------------------------------------------------------------
// bias_cat = [b_kqv (2560) | b_p (96) | zeros (32)]
// ---------------------------------------------------------------------------
__global__ __launch_bounds__(256) void concat_bias(
    const float* __restrict__ b_kqv, const float* __restrict__ b_p,
    float* __restrict__ bc) {
  int i = blockIdx.x * 256 + threadIdx.x;
  if (i >= NKQVC) return;
  bc[i] = (i < 2560) ? b_kqv[i] : (i < 2656 ? b_p[i - 2560] : 0.f);
}

// ---------------------------------------------------------------------------
// MFMA GEMM: C[M,N] = A[M,K] @ Bt[N,K]^T + bias.  A,Bt bf16.
// 128x128 tile, BK=32, 256 threads (4 waves 2x2), 16x16x32 MFMA.
// Double-buffered LDS staging, ONE barrier per K-step (T3-min schedule):
//   stage(next) -> ds_read(cur) -> MFMA -> barrier.
// Epilogue: bf16 out goes through LDS for coalesced 16B stores.
// Requires M%128==0, N%128==0, K%32==0, grid%8==0.
// ---------------------------------------------------------------------------
template <int OUT_BF16>
__global__ __launch_bounds__(256) void gemm_bt_mfma(
    const short* __restrict__ A, const short* __restrict__ Bt,
    const float* __restrict__ bias, void* __restrict__ Cout,
    int M, int N, int K) {
  // dbuf: [buf][A|B][128 rows][32 k] shorts; 16384 shorts = 32 KB total.
  __shared__ __align__(16) short lds[16384];

  // XCD-aware bijective swizzle
  int nwg = gridDim.x;
  int cpx = nwg >> 3;
  int bid = blockIdx.x;
  int swz = (bid & 7) * cpx + (bid >> 3);
  int nbx = N >> 7;
  int bm0 = (swz / nbx) << 7;
  int bn0 = (swz % nbx) << 7;

  const int tid = threadIdx.x;
  const int w = tid >> 6, l = tid & 63;
  const int wm = w >> 1, wn = w & 1;
  const int fr = l & 15;
  const int fq = l >> 4;

  const int ca = w * 2;   // this wave stages chunks ca, ca+1 (16 rows each)
  const short* Ag0 = A + (size_t)(bm0 + ca * 16 + (l >> 2)) * K + (l & 3) * 8;
  const short* Ag1 = Ag0 + (size_t)16 * K;
  const short* Bg0 = Bt + (size_t)(bn0 + ca * 16 + (l >> 2)) * K + (l & 3) * 8;
  const short* Bg1 = Bg0 + (size_t)16 * K;

  f32x4 acc[4][4];
#pragma unroll
  for (int mi = 0; mi < 4; ++mi)
#pragma unroll
    for (int ni = 0; ni < 4; ++ni)
#pragma unroll
      for (int r = 0; r < 4; ++r) acc[mi][ni][r] = 0.f;

  const int KT = K >> 5;
  int cur = 0;
  // prologue: stage tile 0 into buf 0
  {
    short* la = &lds[ca * 512];
    short* lb = &lds[4096 + ca * 512];
    gload16(Ag0, la);
    gload16(Ag1, la + 512);
    gload16(Bg0, lb);
    gload16(Bg1, lb + 512);
  }
  __syncthreads();

  for (int kt = 0; kt < KT; ++kt) {
    // issue next-tile staging first (overlaps with ds_read + MFMA below)
    if (kt + 1 < KT) {
      int nb = (cur ^ 1) * 8192;
      int ko = (kt + 1) * 32;
      short* la = &lds[nb + ca * 512];
      short* lb = &lds[nb + 4096 + ca * 512];
      gload16(Ag0 + ko, la);
      gload16(Ag1 + ko, la + 512);
      gload16(Bg0 + ko, lb);
      gload16(Bg1 + ko, lb + 512);
    }
    const short* ArP = &lds[cur * 8192 + (wm * 64 + fr) * 32 + fq * 8];
    const short* BrP = &lds[cur * 8192 + 4096 + (wn * 64 + fr) * 32 + fq * 8];
    bf16x8 af[4], bfv[4];
#pragma unroll
    for (int mi = 0; mi < 4; ++mi) af[mi] = *(const bf16x8*)(ArP + mi * 512);
#pragma unroll
    for (int ni = 0; ni < 4; ++ni) bfv[ni] = *(const bf16x8*)(BrP + ni * 512);
#pragma unroll
    for (int mi = 0; mi < 4; ++mi)
#pragma unroll
      for (int ni = 0; ni < 4; ++ni)
        acc[mi][ni] = __builtin_amdgcn_mfma_f32_16x16x32_bf16(
            af[mi], bfv[ni], acc[mi][ni], 0, 0, 0);
    __syncthreads();   // drains own stage (vmcnt) + lgkm; all waves synced
    cur ^= 1;
  }

  // C/D layout: col = lane&15, row = (lane>>4)*4 + reg  [m89 verified]
  if (OUT_BF16) {
    // stage C tile in LDS (reusing staging space), then coalesced 16B stores
#pragma unroll
    for (int ni = 0; ni < 4; ++ni) {
      int col = wn * 64 + ni * 16 + fr;
      float bz = bias[bn0 + col];
#pragma unroll
      for (int mi = 0; mi < 4; ++mi) {
        int row = wm * 64 + mi * 16 + fq * 4;
#pragma unroll
        for (int r = 0; r < 4; ++r)
          lds[(row + r) * 128 + col] = f2bf(acc[mi][ni][r] + bz);
      }
    }
    __syncthreads();
    int row = tid >> 1, half = tid & 1;
    const f32x4* src = (const f32x4*)&lds[row * 128 + half * 64];
    f32x4* dst = (f32x4*)((short*)Cout + (size_t)(bm0 + row) * N + bn0 + half * 64);
#pragma unroll
    for (int i = 0; i < 8; ++i) dst[i] = src[i];
  } else {
#pragma unroll
    for (int ni = 0; ni < 4; ++ni) {
      int col = bn0 + wn * 64 + ni * 16 + fr;
      float bz = bias[col];
#pragma unroll
      for (int mi = 0; mi < 4; ++mi) {
        int row = bm0 + wm * 64 + mi * 16 + fq * 4;
#pragma unroll
        for (int r = 0; r < 4; ++r)
          ((float*)Cout)[(size_t)(row + r) * N + col] = acc[mi][ni][r] + bz;
      }
    }
  }
}

// ---------------------------------------------------------------------------
// occil[t][r] = cos((tick + t + 1) * omega_r), omega = linspace(-pi, pi, 7)
// ---------------------------------------------------------------------------
__global__ __launch_bounds__(256) void occil_kernel(const float* __restrict__ tick,
                                                    float* __restrict__ occ) {
  int t = blockIdx.x * 256 + threadIdx.x;
  if (t >= T_SEQ) return;
  float tickt = tick[0] + (float)(t + 1);
#pragma unroll
  for (int r = 0; r < NR; ++r) {
    float om = (float)(-3.14159265358979323846 + r * (3.14159265358979323846 / 3.0));
    occ[t * 8 + r] = cosf(tickt * om);
  }
  occ[t * 8 + 7] = 0.f;
}

// ---------------------------------------------------------------------------
// Pass A: per (chunk, head, dd) local scan end-states + discount products.
// ysum layout: [c][h][slot(44)][dd]; slots: fk r*4+n (0..27), fv 28+r,
// fs 35+n, Pg 39+n, Pb 43.
// ---------------------------------------------------------------------------
__global__ __launch_bounds__(64) void pass_a(
    const short* __restrict__ kqv, const float* __restrict__ occ,
    const int* __restrict__ term, float* __restrict__ ysum) {
  const int c = blockIdx.x, h = blockIdx.y, dd = threadIdx.x;
  __shared__ float sp[CHUNK][12];
  __shared__ float socc[CHUNK][8];
  __shared__ float snt[CHUNK];
  for (int i = dd; i < CHUNK * 12; i += 64) {
    int t = i / 12, j = i - t * 12;
    sp[t][j] = bf2f(kqv[(size_t)(c * CHUNK + t) * NKQVC + 2560 + h * 12 + j]);
  }
  for (int i = dd; i < CHUNK * 8; i += 64)
    socc[i >> 3][i & 7] = occ[(size_t)c * CHUNK * 8 + i];
  for (int t = dd; t < CHUNK; t += 64)
    snt[t] = 1.f - (float)term[c * CHUNK + t];
  __syncthreads();

  float yk[NR][ETA], yv[NR], ys[ETA], Pg[ETA], Pb = 1.f;
#pragma unroll
  for (int r = 0; r < NR; ++r) {
    yv[r] = 0.f;
#pragma unroll
    for (int n = 0; n < ETA; ++n) yk[r][n] = 0.f;
  }
#pragma unroll
  for (int n = 0; n < ETA; ++n) { ys[n] = 0.f; Pg[n] = 1.f; }

  size_t bcur = (size_t)(c * CHUNK) * NKQVC + h * 320 + dd;
  short ck = kqv[bcur], cv = kqv[bcur + 128], cbt = kqv[bcur + 192], cg = kqv[bcur + 256];
  for (int t = 0; t < CHUNK; ++t) {
    size_t bnx = bcur + (t < CHUNK - 1 ? NKQVC : 0);
    short nk = kqv[bnx], nv = kqv[bnx + 128], nbt = kqv[bnx + 192], ng = kqv[bnx + 256];

    float nt = snt[t];
    float rk = fmaxf(bf2f(ck), 0.f);
    float sg = sigm(bf2f(cg));
    float sb = sigm(bf2f(cbt));
    float occr[NR];
#pragma unroll
    for (int r = 0; r < NR; ++r) occr[r] = socc[t][r];
#pragma unroll
    for (int n = 0; n < ETA; ++n) {
      float rp1 = fmaxf(sp[t][n], 0.f);
      float sp3 = sigm(sp[t][8 + n]);
      float gam = sg * sp3;
      float xs  = rk * rp1 * gam;
      float dg  = (1.f - gam) * nt;
      Pg[n] *= dg;
      ys[n] = fmaf(ys[n], dg, xs);
#pragma unroll
      for (int r = 0; r < NR; ++r)
        yk[r][n] = fmaf(yk[r][n], dg, xs * occr[r]);
    }
    float vb = bf2f(cv) * sb;
    float db = (1.f - sb) * nt;
    Pb *= db;
#pragma unroll
    for (int r = 0; r < NR; ++r) yv[r] = fmaf(yv[r], db, vb * occr[r]);

    ck = nk; cv = nv; cbt = nbt; cg = ng; bcur = bnx;
  }

  float* o = ysum + (size_t)(c * NH + h) * 44 * 64 + dd;
#pragma unroll
  for (int r = 0; r < NR; ++r)
#pragma unroll
    for (int n = 0; n < ETA; ++n) o[(r * 4 + n) * 64] = yk[r][n];
#pragma unroll
  for (int r = 0; r < NR; ++r) o[(28 + r) * 64] = yv[r];
#pragma unroll
  for (int n = 0; n < ETA; ++n) o[(35 + n) * 64] = ys[n];
#pragma unroll
  for (int n = 0; n < ETA; ++n) o[(39 + n) * 64] = Pg[n];
  o[43 * 64] = Pb;
}

// ---------------------------------------------------------------------------
// Pass B: carry propagation IN-PLACE in ysum (y-slots overwritten with
// carry-in after being read; P-slots read-only). Software-pipelined: next
// chunk's loads issue before the dependent fma. One thread per chain.
// ---------------------------------------------------------------------------
__global__ __launch_bounds__(256) void pass_b(
    float* __restrict__ ysum, const float* __restrict__ k_prev,
    const float* __restrict__ v_prev, const float* __restrict__ s_prev) {
  int idx = blockIdx.x * 256 + threadIdx.x;
  int dd = idx & 63;
  int slot = (idx >> 6) % 39;
  int h = idx / (39 * 64);

  int pslot;
  float f;
  if (slot < 28) {
    int r = slot >> 2, n = slot & 3;
    f = k_prev[(size_t)(r * NH + h) * 256 + n * 64 + dd];
    pslot = 39 + n;
  } else if (slot < 35) {
    int r = slot - 28;
    f = v_prev[(size_t)(r * NH + h) * 64 + dd];
    pslot = 43;
  } else {
    int n = slot - 35;
    f = s_prev[(size_t)h * 256 + n * 64 + dd];
    pslot = 39 + n;
  }
  const size_t STRIDE = (size_t)NH * 2816;  // 44*64 per head
  float* yb = ysum + (size_t)h * 2816 + slot * 64 + dd;
  const float* pb = ysum + (size_t)h * 2816 + pslot * 64 + dd;
  float y0 = yb[0], p0 = pb[0];
#pragma unroll 8
  for (int c = 0; c < NCHUNK - 1; ++c) {
    size_t o = (size_t)c * STRIDE;
    float yn = yb[o + STRIDE];     // prefetch next before dependent fma
    float pn = pb[o + STRIDE];
    yb[o] = f;                     // carry-in for chunk c (y already read)
    f = fmaf(f, p0, y0);
    y0 = yn; p0 = pn;
  }
  yb[(size_t)(NCHUNK - 1) * STRIDE] = f;
}

// ---------------------------------------------------------------------------
// Pass C: replay chunk with carry-in (in-place ysum, slots 0..38);
// fused kdq/norm/kv dots; attn out (bf16). Last chunk writes final states.
// ---------------------------------------------------------------------------
__global__ __launch_bounds__(64) void pass_c(
    const short* __restrict__ kqv, const float* __restrict__ occ,
    const int* __restrict__ term, const float* __restrict__ carry,
    short* __restrict__ attn, float* __restrict__ out,
    const float* __restrict__ tick) {
  const int c = blockIdx.x, h = blockIdx.y, dd = threadIdx.x;
  __shared__ float sp[CHUNK][12];
  __shared__ float socc[CHUNK][8];
  __shared__ float snt[CHUNK];
  for (int i = dd; i < CHUNK * 12; i += 64) {
    int t = i / 12, j = i - t * 12;
    sp[t][j] = bf2f(kqv[(size_t)(c * CHUNK + t) * NKQVC + 2560 + h * 12 + j]);
  }
  for (int i = dd; i < CHUNK * 8; i += 64)
    socc[i >> 3][i & 7] = occ[(size_t)c * CHUNK * 8 + i];
  for (int t = dd; t < CHUNK; t += 64)
    snt[t] = 1.f - (float)term[c * CHUNK + t];

  const float* cp = carry + (size_t)(c * NH + h) * 2816 + dd;
  float fk[NR][ETA], fv[NR], fs[ETA];
#pragma unroll
  for (int r = 0; r < NR; ++r) {
#pragma unroll
    for (int n = 0; n < ETA; ++n) fk[r][n] = cp[(r * 4 + n) * 64];
    fv[r] = cp[(28 + r) * 64];
  }
#pragma unroll
  for (int n = 0; n < ETA; ++n) fs[n] = cp[(35 + n) * 64];
  __syncthreads();

  size_t bcur = (size_t)(c * CHUNK) * NKQVC + h * 320 + dd;
  short ck = kqv[bcur], cq = kqv[bcur + 64], cv = kqv[bcur + 128],
        cbt = kqv[bcur + 192], cg = kqv[bcur + 256];
  for (int t = 0; t < CHUNK; ++t) {
    size_t bnx = bcur + (t < CHUNK - 1 ? NKQVC : 0);
    short nk = kqv[bnx], nq = kqv[bnx + 64], nv = kqv[bnx + 128],
          nbt = kqv[bnx + 192], ng = kqv[bnx + 256];

    float nt = snt[t];
    float rk = fmaxf(bf2f(ck), 0.f);
    float rq = fmaxf(bf2f(cq), 0.f);
    float sg = sigm(bf2f(cg));
    float sb = sigm(bf2f(cbt));
    float occr[NR];
#pragma unroll
    for (int r = 0; r < NR; ++r) occr[r] = socc[t][r];
    float kdqp[NR];
#pragma unroll
    for (int r = 0; r < NR; ++r) kdqp[r] = 0.f;
    float normp = 0.f;
#pragma unroll
    for (int n = 0; n < ETA; ++n) {
      float rp1 = fmaxf(sp[t][n], 0.f);
      float rp2 = fmaxf(sp[t][4 + n], 0.f);
      float sp3 = sigm(sp[t][8 + n]);
      float gam = sg * sp3;
      float xs  = rk * rp1 * gam;
      float dg  = (1.f - gam) * nt;
      float qf  = rq * rp2;
      fs[n] = fmaf(fs[n], dg, xs);
      normp = fmaf(fs[n], qf, normp);
#pragma unroll
      for (int r = 0; r < NR; ++r) {
        fk[r][n] = fmaf(fk[r][n], dg, xs * occr[r]);
        kdqp[r]  = fmaf(fk[r][n], qf, kdqp[r]);
      }
    }
    float vb = bf2f(cv) * sb;
    float db = (1.f - sb) * nt;
#pragma unroll
    for (int r = 0; r < NR; ++r) fv[r] = fmaf(fv[r], db, vb * occr[r]);

    // 8 butterfly sum-reductions across the 64-lane wave
    float red[8];
#pragma unroll
    for (int r = 0; r < NR; ++r) red[r] = kdqp[r];
    red[7] = normp;
#pragma unroll
    for (int i = 0; i < 8; ++i) {
      float x = red[i];
#pragma unroll
      for (int m = 1; m < 64; m <<= 1) x += __shfl_xor(x, m, 64);
      red[i] = x;
    }
    float denom = fmaf(14.f, red[7], 1e-5f);  // 2*R*norm + eps
    float kvv = 0.f;
#pragma unroll
    for (int r = 0; r < NR; ++r) kvv = fmaf(fv[r], red[r], kvv);
    attn[(size_t)(c * CHUNK + t) * 512 + h * 64 + dd] = f2bf(kvv / denom);

    ck = nk; cq = nq; cv = nv; cbt = nbt; cg = ng; bcur = bnx;
  }

  if (c == NCHUNK - 1) {
#pragma unroll
    for (int r = 0; r < NR; ++r) {
#pragma unroll
      for (int n = 0; n < ETA; ++n)
        out[O_FK + (size_t)(r * NH + h) * 256 + n * 64 + dd] = fk[r][n];
      out[O_FV + (size_t)(r * NH + h) * 64 + dd] = fv[r];
    }
#pragma unroll
    for (int n = 0; n < ETA; ++n)
      out[O_FS + (size_t)h * 256 + n * 64 + dd] = fs[n];
    if (h == 0 && dd == 0) out[O_TICK] = tick[0] + (float)T_SEQ;
  }
}

// ---------------------------------------------------------------------------
extern "C" void kernel_launch(void* const* d_in, const int* in_sizes, int n_in,
                              void* d_out, int out_size, void* d_ws, size_t ws_size,
                              hipStream_t stream) {
  const float* inputs = (const float*)d_in[0];
  const int*   term   = (const int*)d_in[1];
  const float* k_prev = (const float*)d_in[2];
  const float* v_prev = (const float*)d_in[3];
  const float* s_prev = (const float*)d_in[4];
  const float* tick   = (const float*)d_in[5];
  const float* W_kqv  = (const float*)d_in[6];
  const float* b_kqv  = (const float*)d_in[7];
  const float* W_p    = (const float*)d_in[8];
  const float* b_p    = (const float*)d_in[9];
  const float* W_proj = (const float*)d_in[10];
  const float* b_proj = (const float*)d_in[11];
  float* out = (float*)d_out;
  float* ws  = (float*)d_ws;

  short* kqvc   = (short*)(ws + KQVC_OFF);
  float* occ    = ws + OCC_OFF;
  short* BtProj = (short*)(ws + BTPROJ_OFF);
  short* attnbf = (short*)(ws + ATTNBF_OFF);
  float* biasc  = ws + BIASC_OFF;
  short* Abf    = (short*)(ws + ABF_OFF);
  short* BtCat  = (short*)(ws + BTCAT_OFF);
  float* ysum   = ws + YSUM_OFF;   // overlays Abf/BtCat after input GEMM

  // 0) casts, weight transposes (bf16), bias concat
  cast_f32_bf16<<<4096, 256, 0, stream>>>(inputs, Abf);
  transpose_cast<<<dim3(80, 32), dim3(32, 8), 0, stream>>>(W_kqv, BtCat, 1024, 2560);
  transpose_cast<<<dim3(3, 32), dim3(32, 8), 0, stream>>>(
      W_p, BtCat + (size_t)2560 * 1024, 1024, 96);
  transpose_cast<<<dim3(32, 16), dim3(32, 8), 0, stream>>>(W_proj, BtProj, 512, 1024);
  concat_bias<<<11, 256, 0, stream>>>(b_kqv, b_p, biasc);

  // 1) oscillation table
  occil_kernel<<<16, 256, 0, stream>>>(tick, occ);

  // 2) combined kqv+p projection (MFMA, bf16 out): N = 2688
  gemm_bt_mfma<1><<<672, 256, 0, stream>>>(Abf, BtCat, biasc, kqvc,
                                           T_SEQ, NKQVC, DIM);

  // 3) chunked linear scan (transient-A region now dead; ysum overlays it)
  pass_a<<<dim3(NCHUNK, NH), 64, 0, stream>>>(kqvc, occ, term, ysum);
  pass_b<<<78, 256, 0, stream>>>(ysum, k_prev, v_prev, s_prev);
  pass_c<<<dim3(NCHUNK, NH), 64, 0, stream>>>(kqvc, occ, term, ysum,
                                              attnbf, out, tick);

  // 4) output projection (MFMA, f32 out)
  gemm_bt_mfma<0><<<256, 256, 0, stream>>>(attnbf, BtProj, b_proj, out,
                                           T_SEQ, DIM, NH * HDIM);
}

// Round 5
// 143.007 us; speedup vs baseline: 4.2374x; 1.1496x over previous
//
#include <hip/hip_runtime.h>
#include <hip/hip_bf16.h>
#include <math.h>

// Problem constants
#define T_SEQ 4096
#define DIM   1024
#define NH    8
#define HDIM  64
#define ETA   4
#define NR    7
#define NKQVC 2688   // combined: 2560 kqv + 96 p + 32 pad
#define CHUNK 16
#define NCHUNK 256   // T_SEQ / CHUNK

typedef __attribute__((ext_vector_type(8))) short bf16x8;
typedef __attribute__((ext_vector_type(4))) short short4v;
typedef __attribute__((ext_vector_type(4))) float f32x4;

// Workspace layout (float offsets). Total 12,618,496 fl = 50.5 MB.
// Permanent:
#define KQVC_OFF    0ul          // combined kqv+p bf16: 4096*2688 sh = 5,505,024 fl
#define OCC_OFF     5505024ul    // occ f32: 4096*8 = 32,768 fl
#define BTPROJ_OFF  5537792ul    // W_proj^T bf16: 1024*512 sh = 262,144 fl
#define ATTNBF_OFF  5799936ul    // attn bf16: 4096*512 sh = 1,048,576 fl
#define BIASC_OFF   6848512ul    // concat bias f32: 2,816 fl
// Transient A (dead after input GEMM):
#define ABF_OFF     6851328ul    // inputs bf16: 2,097,152 fl
#define BTCAT_OFF   8948480ul    // [2688][1024] bf16 = 1,376,256 fl
// Transient B (overlays transient A after GEMM; carry in-place):
#define YSUM_OFF    6851328ul    // 256*8*44*64 = 5,767,168 fl

// Output layout (float offsets), concatenated in return order
#define O_ATTN 0ul
#define O_FK   4194304ul   // (7,8,256)
#define O_FV   4208640ul   // (7,8,64)
#define O_FS   4212224ul   // (8,256)
#define O_TICK 4214272ul   // (1,)

__device__ __forceinline__ float sigm(float x) { return 1.f / (1.f + __expf(-x)); }

__device__ __forceinline__ short f2bf(float f) {
  union { __hip_bfloat16 b; short s; } u;
  u.b = __float2bfloat16(f);
  return u.s;
}
__device__ __forceinline__ float bf2f(short s) {
  union { __hip_bfloat16 b; short s2; } u;
  u.s2 = s;
  return __bfloat162float(u.b);
}

__device__ __forceinline__ void gload16(const void* g, void* l) {
  __builtin_amdgcn_global_load_lds(
      (const __attribute__((address_space(1))) void*)g,
      (__attribute__((address_space(3))) void*)l, 16, 0, 0);
}

// ---------------------------------------------------------------------------
// Cast f32 -> bf16, 4 elements/thread.
// ---------------------------------------------------------------------------
__global__ __launch_bounds__(256) void cast_f32_bf16(
    const float* __restrict__ x, short* __restrict__ y) {
  size_t i = (size_t)(blockIdx.x * 256 + threadIdx.x) * 4;
  float4 v = *(const float4*)(x + i);
  short4v o;
  o.x = f2bf(v.x); o.y = f2bf(v.y); o.z = f2bf(v.z); o.w = f2bf(v.w);
  *(short4v*)(y + i) = o;
}

// ---------------------------------------------------------------------------
// Transposing cast: W [K][N] f32 -> Bt [N][K] bf16. 32x32 tiles, block (32,8).
// ---------------------------------------------------------------------------
__global__ __launch_bounds__(256) void transpose_cast(
    const float* __restrict__ W, short* __restrict__ Bt, int K, int N) {
  __shared__ float tile[32][33];
  int n0 = blockIdx.x * 32, k0 = blockIdx.y * 32;
  int tx = threadIdx.x, ty = threadIdx.y;
  for (int i = ty; i < 32; i += 8)
    tile[i][tx] = W[(size_t)(k0 + i) * N + n0 + tx];
  __syncthreads();
  for (int i = ty; i < 32; i += 8)
    Bt[(size_t)(n0 + i) * K + k0 + tx] = f2bf(tile[tx][i]);
}

// ---------------------------------------------------------------------------
// bias_cat = [b_kqv (2560) | b_p (96) | zeros (32)]
// ---------------------------------------------------------------------------
__global__ __launch_bounds__(256) void concat_bias(
    const float* __restrict__ b_kqv, const float* __restrict__ b_p,
    float* __restrict__ bc) {
  int i = blockIdx.x * 256 + threadIdx.x;
  if (i >= NKQVC) return;
  bc[i] = (i < 2560) ? b_kqv[i] : (i < 2656 ? b_p[i - 2560] : 0.f);
}

// ---------------------------------------------------------------------------
// MFMA GEMM: C[M,N] = A[M,K] @ Bt[N,K]^T + bias.  A,Bt bf16.
// 128x128 tile, BK=32, 256 threads (4 waves 2x2), 16x16x32 MFMA.
// Double-buffered LDS staging, ONE barrier per K-step:
//   stage(next) -> ds_read(cur) -> MFMA -> barrier.
// ---------------------------------------------------------------------------
template <int OUT_BF16>
__global__ __launch_bounds__(256) void gemm_bt_mfma(
    const short* __restrict__ A, const short* __restrict__ Bt,
    const float* __restrict__ bias, void* __restrict__ Cout,
    int M, int N, int K) {
  __shared__ __align__(16) short lds[16384];

  // XCD-aware bijective swizzle
  int nwg = gridDim.x;
  int cpx = nwg >> 3;
  int bid = blockIdx.x;
  int swz = (bid & 7) * cpx + (bid >> 3);
  int nbx = N >> 7;
  int bm0 = (swz / nbx) << 7;
  int bn0 = (swz % nbx) << 7;

  const int tid = threadIdx.x;
  const int w = tid >> 6, l = tid & 63;
  const int wm = w >> 1, wn = w & 1;
  const int fr = l & 15;
  const int fq = l >> 4;

  const int ca = w * 2;
  const short* Ag0 = A + (size_t)(bm0 + ca * 16 + (l >> 2)) * K + (l & 3) * 8;
  const short* Ag1 = Ag0 + (size_t)16 * K;
  const short* Bg0 = Bt + (size_t)(bn0 + ca * 16 + (l >> 2)) * K + (l & 3) * 8;
  const short* Bg1 = Bg0 + (size_t)16 * K;

  f32x4 acc[4][4];
#pragma unroll
  for (int mi = 0; mi < 4; ++mi)
#pragma unroll
    for (int ni = 0; ni < 4; ++ni)
#pragma unroll
      for (int r = 0; r < 4; ++r) acc[mi][ni][r] = 0.f;

  const int KT = K >> 5;
  int cur = 0;
  {
    short* la = &lds[ca * 512];
    short* lb = &lds[4096 + ca * 512];
    gload16(Ag0, la);
    gload16(Ag1, la + 512);
    gload16(Bg0, lb);
    gload16(Bg1, lb + 512);
  }
  __syncthreads();

  for (int kt = 0; kt < KT; ++kt) {
    if (kt + 1 < KT) {
      int nb = (cur ^ 1) * 8192;
      int ko = (kt + 1) * 32;
      short* la = &lds[nb + ca * 512];
      short* lb = &lds[nb + 4096 + ca * 512];
      gload16(Ag0 + ko, la);
      gload16(Ag1 + ko, la + 512);
      gload16(Bg0 + ko, lb);
      gload16(Bg1 + ko, lb + 512);
    }
    const short* ArP = &lds[cur * 8192 + (wm * 64 + fr) * 32 + fq * 8];
    const short* BrP = &lds[cur * 8192 + 4096 + (wn * 64 + fr) * 32 + fq * 8];
    bf16x8 af[4], bfv[4];
#pragma unroll
    for (int mi = 0; mi < 4; ++mi) af[mi] = *(const bf16x8*)(ArP + mi * 512);
#pragma unroll
    for (int ni = 0; ni < 4; ++ni) bfv[ni] = *(const bf16x8*)(BrP + ni * 512);
#pragma unroll
    for (int mi = 0; mi < 4; ++mi)
#pragma unroll
      for (int ni = 0; ni < 4; ++ni)
        acc[mi][ni] = __builtin_amdgcn_mfma_f32_16x16x32_bf16(
            af[mi], bfv[ni], acc[mi][ni], 0, 0, 0);
    __syncthreads();
    cur ^= 1;
  }

  // C/D layout: col = lane&15, row = (lane>>4)*4 + reg  [m89 verified]
  if (OUT_BF16) {
#pragma unroll
    for (int ni = 0; ni < 4; ++ni) {
      int col = wn * 64 + ni * 16 + fr;
      float bz = bias[bn0 + col];
#pragma unroll
      for (int mi = 0; mi < 4; ++mi) {
        int row = wm * 64 + mi * 16 + fq * 4;
#pragma unroll
        for (int r = 0; r < 4; ++r)
          lds[(row + r) * 128 + col] = f2bf(acc[mi][ni][r] + bz);
      }
    }
    __syncthreads();
    int row = tid >> 1, half = tid & 1;
    const f32x4* src = (const f32x4*)&lds[row * 128 + half * 64];
    f32x4* dst = (f32x4*)((short*)Cout + (size_t)(bm0 + row) * N + bn0 + half * 64);
#pragma unroll
    for (int i = 0; i < 8; ++i) dst[i] = src[i];
  } else {
#pragma unroll
    for (int ni = 0; ni < 4; ++ni) {
      int col = bn0 + wn * 64 + ni * 16 + fr;
      float bz = bias[col];
#pragma unroll
      for (int mi = 0; mi < 4; ++mi) {
        int row = bm0 + wm * 64 + mi * 16 + fq * 4;
#pragma unroll
        for (int r = 0; r < 4; ++r)
          ((float*)Cout)[(size_t)(row + r) * N + col] = acc[mi][ni][r] + bz;
      }
    }
  }
}

// ---------------------------------------------------------------------------
// occil[t][r] = cos((tick + t + 1) * omega_r), omega = linspace(-pi, pi, 7)
// ---------------------------------------------------------------------------
__global__ __launch_bounds__(256) void occil_kernel(const float* __restrict__ tick,
                                                    float* __restrict__ occ) {
  int t = blockIdx.x * 256 + threadIdx.x;
  if (t >= T_SEQ) return;
  float tickt = tick[0] + (float)(t + 1);
#pragma unroll
  for (int r = 0; r < NR; ++r) {
    float om = (float)(-3.14159265358979323846 + r * (3.14159265358979323846 / 3.0));
    occ[t * 8 + r] = cosf(tickt * om);
  }
  occ[t * 8 + 7] = 0.f;
}

// ---------------------------------------------------------------------------
// Pass A: per (chunk, head, dd) local scan end-states + discount products.
// ysum layout: [c][h][slot(44)][dd]; slots: fk r*4+n (0..27), fv 28+r,
// fs 35+n, Pg 39+n, Pb 43.
// ---------------------------------------------------------------------------
__global__ __launch_bounds__(64) void pass_a(
    const short* __restrict__ kqv, const float* __restrict__ occ,
    const int* __restrict__ term, float* __restrict__ ysum) {
  const int c = blockIdx.x, h = blockIdx.y, dd = threadIdx.x;
  __shared__ float sp[CHUNK][12];
  __shared__ float socc[CHUNK][8];
  __shared__ float snt[CHUNK];
  for (int i = dd; i < CHUNK * 12; i += 64) {
    int t = i / 12, j = i - t * 12;
    sp[t][j] = bf2f(kqv[(size_t)(c * CHUNK + t) * NKQVC + 2560 + h * 12 + j]);
  }
  for (int i = dd; i < CHUNK * 8; i += 64)
    socc[i >> 3][i & 7] = occ[(size_t)c * CHUNK * 8 + i];
  for (int t = dd; t < CHUNK; t += 64)
    snt[t] = 1.f - (float)term[c * CHUNK + t];
  __syncthreads();

  float yk[NR][ETA], yv[NR], ys[ETA], Pg[ETA], Pb = 1.f;
#pragma unroll
  for (int r = 0; r < NR; ++r) {
    yv[r] = 0.f;
#pragma unroll
    for (int n = 0; n < ETA; ++n) yk[r][n] = 0.f;
  }
#pragma unroll
  for (int n = 0; n < ETA; ++n) { ys[n] = 0.f; Pg[n] = 1.f; }

  size_t bcur = (size_t)(c * CHUNK) * NKQVC + h * 320 + dd;
  short ck = kqv[bcur], cv = kqv[bcur + 128], cbt = kqv[bcur + 192], cg = kqv[bcur + 256];
  for (int t = 0; t < CHUNK; ++t) {
    size_t bnx = bcur + (t < CHUNK - 1 ? NKQVC : 0);
    short nk = kqv[bnx], nv = kqv[bnx + 128], nbt = kqv[bnx + 192], ng = kqv[bnx + 256];

    float nt = snt[t];
    float rk = fmaxf(bf2f(ck), 0.f);
    float sg = sigm(bf2f(cg));
    float sb = sigm(bf2f(cbt));
    float occr[NR];
#pragma unroll
    for (int r = 0; r < NR; ++r) occr[r] = socc[t][r];
#pragma unroll
    for (int n = 0; n < ETA; ++n) {
      float rp1 = fmaxf(sp[t][n], 0.f);
      float sp3 = sigm(sp[t][8 + n]);
      float gam = sg * sp3;
      float xs  = rk * rp1 * gam;
      float dg  = (1.f - gam) * nt;
      Pg[n] *= dg;
      ys[n] = fmaf(ys[n], dg, xs);
#pragma unroll
      for (int r = 0; r < NR; ++r)
        yk[r][n] = fmaf(yk[r][n], dg, xs * occr[r]);
    }
    float vb = bf2f(cv) * sb;
    float db = (1.f - sb) * nt;
    Pb *= db;
#pragma unroll
    for (int r = 0; r < NR; ++r) yv[r] = fmaf(yv[r], db, vb * occr[r]);

    ck = nk; cv = nv; cbt = nbt; cg = ng; bcur = bnx;
  }

  float* o = ysum + (size_t)(c * NH + h) * 44 * 64 + dd;
#pragma unroll
  for (int r = 0; r < NR; ++r)
#pragma unroll
    for (int n = 0; n < ETA; ++n) o[(r * 4 + n) * 64] = yk[r][n];
#pragma unroll
  for (int r = 0; r < NR; ++r) o[(28 + r) * 64] = yv[r];
#pragma unroll
  for (int n = 0; n < ETA; ++n) o[(35 + n) * 64] = ys[n];
#pragma unroll
  for (int n = 0; n < ETA; ++n) o[(39 + n) * 64] = Pg[n];
  o[43 * 64] = Pb;
}

// ---------------------------------------------------------------------------
// Pass B: carry propagation IN-PLACE in ysum (y-slots overwritten with
// carry-in after being read; P-slots read-only). Ring-buffer prefetch with
// distance 16: all indices compile-time (full unroll) so the ring stays in
// VGPRs. The 16 next-body loads issue before the serial fma chain, giving
// ~16 loads in flight per wave instead of 1.
// ---------------------------------------------------------------------------
__global__ __launch_bounds__(256) void pass_b(
    float* __restrict__ ysum, const float* __restrict__ k_prev,
    const float* __restrict__ v_prev, const float* __restrict__ s_prev) {
  int idx = blockIdx.x * 256 + threadIdx.x;
  int dd = idx & 63;
  int slot = (idx >> 6) % 39;
  int h = idx / (39 * 64);

  int pslot;
  float f;
  if (slot < 28) {
    int r = slot >> 2, n = slot & 3;
    f = k_prev[(size_t)(r * NH + h) * 256 + n * 64 + dd];
    pslot = 39 + n;
  } else if (slot < 35) {
    int r = slot - 28;
    f = v_prev[(size_t)(r * NH + h) * 64 + dd];
    pslot = 43;
  } else {
    int n = slot - 35;
    f = s_prev[(size_t)h * 256 + n * 64 + dd];
    pslot = 39 + n;
  }
  const size_t STRIDE = (size_t)NH * 2816;  // 44*64 per head
  float* yb = ysum + (size_t)h * 2816 + slot * 64 + dd;
  const float* pb = ysum + (size_t)h * 2816 + pslot * 64 + dd;

#define PD 16                       // prefetch distance (ring in VGPRs)
  float yring[PD], pring[PD];
#pragma unroll
  for (int d = 0; d < PD; ++d) {
    yring[d] = yb[(size_t)d * STRIDE];
    pring[d] = pb[(size_t)d * STRIDE];
  }
  const int NB = NCHUNK / PD;       // 16 bodies
  for (int cb = 0; cb < NB; ++cb) {
    int c0 = cb * PD;
    // issue next body's loads first (independent of the fma chain)
    float ynext[PD], pnext[PD];
    if (cb + 1 < NB) {
#pragma unroll
      for (int j = 0; j < PD; ++j) {
        ynext[j] = yb[(size_t)(c0 + PD + j) * STRIDE];
        pnext[j] = pb[(size_t)(c0 + PD + j) * STRIDE];
      }
    }
#pragma unroll
    for (int j = 0; j < PD; ++j) {
      yb[(size_t)(c0 + j) * STRIDE] = f;   // carry-in for chunk c0+j
      f = fmaf(f, pring[j], yring[j]);
    }
    if (cb + 1 < NB) {
#pragma unroll
      for (int j = 0; j < PD; ++j) { yring[j] = ynext[j]; pring[j] = pnext[j]; }
    }
  }
#undef PD
}

// ---------------------------------------------------------------------------
// Pass C: replay chunk with carry-in (in-place ysum, slots 0..38);
// fused kdq/norm/kv dots; attn out (bf16). Last chunk writes final states.
// ---------------------------------------------------------------------------
__global__ __launch_bounds__(64) void pass_c(
    const short* __restrict__ kqv, const float* __restrict__ occ,
    const int* __restrict__ term, const float* __restrict__ carry,
    short* __restrict__ attn, float* __restrict__ out,
    const float* __restrict__ tick) {
  const int c = blockIdx.x, h = blockIdx.y, dd = threadIdx.x;
  __shared__ float sp[CHUNK][12];
  __shared__ float socc[CHUNK][8];
  __shared__ float snt[CHUNK];
  for (int i = dd; i < CHUNK * 12; i += 64) {
    int t = i / 12, j = i - t * 12;
    sp[t][j] = bf2f(kqv[(size_t)(c * CHUNK + t) * NKQVC + 2560 + h * 12 + j]);
  }
  for (int i = dd; i < CHUNK * 8; i += 64)
    socc[i >> 3][i & 7] = occ[(size_t)c * CHUNK * 8 + i];
  for (int t = dd; t < CHUNK; t += 64)
    snt[t] = 1.f - (float)term[c * CHUNK + t];

  const float* cp = carry + (size_t)(c * NH + h) * 2816 + dd;
  float fk[NR][ETA], fv[NR], fs[ETA];
#pragma unroll
  for (int r = 0; r < NR; ++r) {
#pragma unroll
    for (int n = 0; n < ETA; ++n) fk[r][n] = cp[(r * 4 + n) * 64];
    fv[r] = cp[(28 + r) * 64];
  }
#pragma unroll
  for (int n = 0; n < ETA; ++n) fs[n] = cp[(35 + n) * 64];
  __syncthreads();

  size_t bcur = (size_t)(c * CHUNK) * NKQVC + h * 320 + dd;
  short ck = kqv[bcur], cq = kqv[bcur + 64], cv = kqv[bcur + 128],
        cbt = kqv[bcur + 192], cg = kqv[bcur + 256];
  for (int t = 0; t < CHUNK; ++t) {
    size_t bnx = bcur + (t < CHUNK - 1 ? NKQVC : 0);
    short nk = kqv[bnx], nq = kqv[bnx + 64], nv = kqv[bnx + 128],
          nbt = kqv[bnx + 192], ng = kqv[bnx + 256];

    float nt = snt[t];
    float rk = fmaxf(bf2f(ck), 0.f);
    float rq = fmaxf(bf2f(cq), 0.f);
    float sg = sigm(bf2f(cg));
    float sb = sigm(bf2f(cbt));
    float occr[NR];
#pragma unroll
    for (int r = 0; r < NR; ++r) occr[r] = socc[t][r];
    float kdqp[NR];
#pragma unroll
    for (int r = 0; r < NR; ++r) kdqp[r] = 0.f;
    float normp = 0.f;
#pragma unroll
    for (int n = 0; n < ETA; ++n) {
      float rp1 = fmaxf(sp[t][n], 0.f);
      float rp2 = fmaxf(sp[t][4 + n], 0.f);
      float sp3 = sigm(sp[t][8 + n]);
      float gam = sg * sp3;
      float xs  = rk * rp1 * gam;
      float dg  = (1.f - gam) * nt;
      float qf  = rq * rp2;
      fs[n] = fmaf(fs[n], dg, xs);
      normp = fmaf(fs[n], qf, normp);
#pragma unroll
      for (int r = 0; r < NR; ++r) {
        fk[r][n] = fmaf(fk[r][n], dg, xs * occr[r]);
        kdqp[r]  = fmaf(fk[r][n], qf, kdqp[r]);
      }
    }
    float vb = bf2f(cv) * sb;
    float db = (1.f - sb) * nt;
#pragma unroll
    for (int r = 0; r < NR; ++r) fv[r] = fmaf(fv[r], db, vb * occr[r]);

    float red[8];
#pragma unroll
    for (int r = 0; r < NR; ++r) red[r] = kdqp[r];
    red[7] = normp;
#pragma unroll
    for (int i = 0; i < 8; ++i) {
      float x = red[i];
#pragma unroll
      for (int m = 1; m < 64; m <<= 1) x += __shfl_xor(x, m, 64);
      red[i] = x;
    }
    float denom = fmaf(14.f, red[7], 1e-5f);  // 2*R*norm + eps
    float kvv = 0.f;
#pragma unroll
    for (int r = 0; r < NR; ++r) kvv = fmaf(fv[r], red[r], kvv);
    attn[(size_t)(c * CHUNK + t) * 512 + h * 64 + dd] = f2bf(kvv / denom);

    ck = nk; cq = nq; cv = nv; cbt = nbt; cg = ng; bcur = bnx;
  }

  if (c == NCHUNK - 1) {
#pragma unroll
    for (int r = 0; r < NR; ++r) {
#pragma unroll
      for (int n = 0; n < ETA; ++n)
        out[O_FK + (size_t)(r * NH + h) * 256 + n * 64 + dd] = fk[r][n];
      out[O_FV + (size_t)(r * NH + h) * 64 + dd] = fv[r];
    }
#pragma unroll
    for (int n = 0; n < ETA; ++n)
      out[O_FS + (size_t)h * 256 + n * 64 + dd] = fs[n];
    if (h == 0 && dd == 0) out[O_TICK] = tick[0] + (float)T_SEQ;
  }
}

// ---------------------------------------------------------------------------
extern "C" void kernel_launch(void* const* d_in, const int* in_sizes, int n_in,
                              void* d_out, int out_size, void* d_ws, size_t ws_size,
                              hipStream_t stream) {
  const float* inputs = (const float*)d_in[0];
  const int*   term   = (const int*)d_in[1];
  const float* k_prev = (const float*)d_in[2];
  const float* v_prev = (const float*)d_in[3];
  const float* s_prev = (const float*)d_in[4];
  const float* tick   = (const float*)d_in[5];
  const float* W_kqv  = (const float*)d_in[6];
  const float* b_kqv  = (const float*)d_in[7];
  const float* W_p    = (const float*)d_in[8];
  const float* b_p    = (const float*)d_in[9];
  const float* W_proj = (const float*)d_in[10];
  const float* b_proj = (const float*)d_in[11];
  float* out = (float*)d_out;
  float* ws  = (float*)d_ws;

  short* kqvc   = (short*)(ws + KQVC_OFF);
  float* occ    = ws + OCC_OFF;
  short* BtProj = (short*)(ws + BTPROJ_OFF);
  short* attnbf = (short*)(ws + ATTNBF_OFF);
  float* biasc  = ws + BIASC_OFF;
  short* Abf    = (short*)(ws + ABF_OFF);
  short* BtCat  = (short*)(ws + BTCAT_OFF);
  float* ysum   = ws + YSUM_OFF;   // overlays Abf/BtCat after input GEMM

  // 0) casts, weight transposes (bf16), bias concat
  cast_f32_bf16<<<4096, 256, 0, stream>>>(inputs, Abf);
  transpose_cast<<<dim3(80, 32), dim3(32, 8), 0, stream>>>(W_kqv, BtCat, 1024, 2560);
  transpose_cast<<<dim3(3, 32), dim3(32, 8), 0, stream>>>(
      W_p, BtCat + (size_t)2560 * 1024, 1024, 96);
  transpose_cast<<<dim3(32, 16), dim3(32, 8), 0, stream>>>(W_proj, BtProj, 512, 1024);
  concat_bias<<<11, 256, 0, stream>>>(b_kqv, b_p, biasc);

  // 1) oscillation table
  occil_kernel<<<16, 256, 0, stream>>>(tick, occ);

  // 2) combined kqv+p projection (MFMA, bf16 out): N = 2688
  gemm_bt_mfma<1><<<672, 256, 0, stream>>>(Abf, BtCat, biasc, kqvc,
                                           T_SEQ, NKQVC, DIM);

  // 3) chunked linear scan (transient-A region now dead; ysum overlays it)
  pass_a<<<dim3(NCHUNK, NH), 64, 0, stream>>>(kqvc, occ, term, ysum);
  pass_b<<<78, 256, 0, stream>>>(ysum, k_prev, v_prev, s_prev);
  pass_c<<<dim3(NCHUNK, NH), 64, 0, stream>>>(kqvc, occ, term, ysum,
                                              attnbf, out, tick);

  // 4) output projection (MFMA, f32 out)
  gemm_bt_mfma<0><<<256, 256, 0, stream>>>(attnbf, BtProj, b_proj, out,
                                           T_SEQ, DIM, NH * HDIM);
}